// Round 21
// baseline (1181.975 us; speedup 1.0000x reference)
//
#include <hip/hip_runtime.h>
#include <hip/hip_bf16.h>

// ---------------------------------------------------------------------------
// DimeNet++ interaction block, round 21:
//   Round-20 config + fp16 t_lds:
//     - t activations stored fp16 (hi only) -> GEMMs 3..9 (and k1 GEMM2)
//       are single-pass fp16 MFMA (MFMA count -40% in kbig), the per-read
//       split44h VALU work disappears, and t_lds halves ->
//       kbig LDS 50->33.8 KB -> 4 blocks/CU.
//     - GEMM1/2 (fp32 inputs x, W4) keep the 2-pass hi/lo split.
//   Error budget: one 2^-11 activation quantization entering 7 GEMMs;
//   residuals stay fp32 in registers. absmax pinned at 2^-5 since r3.
// ---------------------------------------------------------------------------

typedef __attribute__((ext_vector_type(8))) _Float16 f16x8;
typedef __attribute__((ext_vector_type(4))) float f32x4;

__device__ __forceinline__ float silu_f(float v) {
    return v * __builtin_amdgcn_rcpf(1.0f + __expf(-v));
}

__device__ __forceinline__ void split44h(f32x4 a, f32x4 b, f16x8& hi, f16x8& lo) {
    float f[8] = {a[0], a[1], a[2], a[3], b[0], b[1], b[2], b[3]};
    #pragma unroll
    for (int j = 0; j < 8; ++j) {
        const _Float16 h = (_Float16)f[j];
        hi[j] = h;
        lo[j] = (_Float16)(f[j] - (float)h);
    }
}

__device__ __forceinline__ void gll16(const void* g, void* l) {
    __builtin_amdgcn_global_load_lds((const __attribute__((address_space(1))) void*)g,
                                     (__attribute__((address_space(3))) void*)l, 16, 0, 0);
}
__device__ __forceinline__ void stage8k(const char* g, _Float16* l, int lane, int wid) {
    #pragma unroll
    for (int i = 0; i < 2; ++i) {
        const int off = ((i * 4 + wid) << 10);
        gll16(g + off + lane * 16, (char*)l + off);
    }
}
__device__ __forceinline__ void stage4k(const char* g, _Float16* l, int lane, int wid) {
    const int off = (wid << 10);
    gll16(g + off + lane * 16, (char*)l + off);
}

// 2-pass split-fp16 MFMA (A = fp32 registers split hi/lo)
template<int NF>
__device__ __forceinline__ void mfma_ks(f16x8 ah, f16x8 al, const _Float16* slot,
                                        int acol, int kq, f32x4* acc) {
    #pragma unroll
    for (int n = 0; n < NF; ++n) {
        const int c = n * 16 + acol;
        const int sw = (kq ^ ((c >> 1) & 3)) << 3;
        const f16x8 bh = *(const f16x8*)&slot[c * 32 + sw];
        acc[n] = __builtin_amdgcn_mfma_f32_16x16x32_f16(ah, bh, acc[n], 0, 0, 0);
        acc[n] = __builtin_amdgcn_mfma_f32_16x16x32_f16(al, bh, acc[n], 0, 0, 0);
    }
}

// 1-pass fp16 MFMA (A already fp16)
template<int NF>
__device__ __forceinline__ void mfma_ks1(f16x8 ah, const _Float16* slot,
                                         int acol, int kq, f32x4* acc) {
    #pragma unroll
    for (int n = 0; n < NF; ++n) {
        const int c = n * 16 + acol;
        const int sw = (kq ^ ((c >> 1) & 3)) << 3;
        const f16x8 bh = *(const f16x8*)&slot[c * 32 + sw];
        acc[n] = __builtin_amdgcn_mfma_f32_16x16x32_f16(ah, bh, acc[n], 0, 0, 0);
    }
}

#define TPH 136   // fp16 t_lds pitch in halves (16B-aligned frags, 2-way banks)

__device__ __forceinline__ f16x8 tfrag16(const _Float16* tl, int rb, int q, int kq) {
    return *(const f16x8*)&tl[rb + q * 32 + kq * 8];
}

// 4-phase 128-k GEMM, A = fp16 t_lds (1-pass), B LDS double-buffered
__device__ __forceinline__ void tgemm4h(const char* img, const char* imgnext,
                                        _Float16* sA, _Float16* sB,
                                        const _Float16* tl, int rb,
                                        int kq, int acol, int lane, int wid, f32x4* acc)
{
    f16x8 Ah[4];
    #pragma unroll
    for (int q = 0; q < 4; ++q) Ah[q] = tfrag16(tl, rb, q, kq);

    stage8k(img + 8192, sB, lane, wid);
    mfma_ks1<8>(Ah[0], sA, acol, kq, acc); __syncthreads();
    stage8k(img + 16384, sA, lane, wid);
    mfma_ks1<8>(Ah[1], sB, acol, kq, acc); __syncthreads();
    stage8k(img + 24576, sB, lane, wid);
    mfma_ks1<8>(Ah[2], sA, acol, kq, acc); __syncthreads();
    if (imgnext) stage8k(imgnext, sA, lane, wid);
    mfma_ks1<8>(Ah[3], sB, acol, kq, acc); __syncthreads();
}

// ---------------- fused prologue: wprep | rbf1 | count_rank -----------------
struct WDesc { const float* src; char* dst; int K; int N; };
struct ProArgs {
    WDesc w[11];
    const float* rbf; const float* w_rbf1; float* re1; int E;
    const int* idx_ji; int* cnt; int* rank; int T;
    int nW, nR;
};

__device__ void wprep_body(const ProArgs& P, int b) {
    const WDesc d = P.w[b >> 2];
    const int h = b & 3;
    if (h * 32 >= d.K) return;
    char* slab = d.dst + (size_t)h * d.N * 64;
    for (int idx = threadIdx.x; idx < d.N * 4; idx += 256) {
        const int c = idx >> 2, ch = idx & 3;
        f16x8 v;
        #pragma unroll
        for (int j = 0; j < 8; ++j)
            v[j] = (_Float16)d.src[(size_t)(h * 32 + ch * 8 + j) * d.N + c];
        *(f16x8*)(slab + c * 64 + ((ch ^ ((c >> 1) & 3)) << 4)) = v;
    }
}

__device__ void rbf1_body(const ProArgs& P, int b) {
    const int i = b * 256 + threadIdx.x;
    const int e = i >> 3, p = i & 7;
    if (e < P.E) {
        float s = 0.f;
        #pragma unroll
        for (int q = 0; q < 6; ++q) s = fmaf(P.rbf[e * 6 + q], P.w_rbf1[q * 8 + p], s);
        P.re1[i] = s;
    }
}

__device__ void count_rank_body(const ProArgs& P, int b) {
    const int i = (b * 256 + threadIdx.x) * 4;
    const int T = P.T;
    if (i + 3 < T) {
        const int4 j = *(const int4*)&P.idx_ji[i];
        int4 r;
        r.x = atomicAdd(&P.cnt[j.x], 1);
        r.y = atomicAdd(&P.cnt[j.y], 1);
        r.z = atomicAdd(&P.cnt[j.z], 1);
        r.w = atomicAdd(&P.cnt[j.w], 1);
        *(int4*)&P.rank[i] = r;
    } else {
        for (int k = i; k < T; ++k) P.rank[k] = atomicAdd(&P.cnt[P.idx_ji[k]], 1);
    }
}

__global__ void pro_kernel(ProArgs P) {
    const int b = blockIdx.x;
    if (b < P.nW)             wprep_body(P, b);
    else if (b < P.nW + P.nR) rbf1_body(P, b - P.nW);
    else                      count_rank_body(P, b - P.nW - P.nR);
}

// ---------------- scans ------------------------------------------------------

__global__ void scan_partial_kernel(const int* __restrict__ cnt, int* __restrict__ partial, int E) {
    __shared__ int red[256];
    const int tid = threadIdx.x;
    const int base = blockIdx.x * 1024 + tid * 4;
    int s = 0;
    #pragma unroll
    for (int i = 0; i < 4; ++i) { const int g = base + i; if (g < E) s += cnt[g]; }
    red[tid] = s;
    __syncthreads();
    for (int off = 128; off > 0; off >>= 1) {
        if (tid < off) red[tid] += red[tid + off];
        __syncthreads();
    }
    if (tid == 0) partial[blockIdx.x] = red[0];
}

__global__ void scan_block_kernel(const int* __restrict__ partial, int* __restrict__ blockoff,
                                  int NB, int* offsets, int E) {
    __shared__ int red[256];
    const int tid = threadIdx.x;
    int v[4]; int s = 0;
    #pragma unroll
    for (int i = 0; i < 4; ++i) { const int g = tid * 4 + i; v[i] = (g < NB) ? partial[g] : 0; s += v[i]; }
    red[tid] = s;
    __syncthreads();
    for (int off = 1; off < 256; off <<= 1) {
        const int add = (tid >= off) ? red[tid - off] : 0;
        __syncthreads();
        red[tid] += add;
        __syncthreads();
    }
    int excl = (tid == 0) ? 0 : red[tid - 1];
    #pragma unroll
    for (int i = 0; i < 4; ++i) { const int g = tid * 4 + i; if (g < NB) blockoff[g] = excl; excl += v[i]; }
    if (tid == 255) offsets[E] = red[255];
}

__global__ void scan_final_kernel(const int* __restrict__ cnt, const int* __restrict__ blockoff,
                                  int* __restrict__ offsets, int E) {
    __shared__ int red[256];
    const int tid = threadIdx.x;
    const int base = blockIdx.x * 1024 + tid * 4;
    int v[4]; int s = 0;
    #pragma unroll
    for (int i = 0; i < 4; ++i) { const int g = base + i; v[i] = (g < E) ? cnt[g] : 0; s += v[i]; }
    red[tid] = s;
    __syncthreads();
    for (int off = 1; off < 256; off <<= 1) {
        const int add = (tid >= off) ? red[tid - off] : 0;
        __syncthreads();
        red[tid] += add;
        __syncthreads();
    }
    int run = blockoff[blockIdx.x] + ((tid == 0) ? 0 : red[tid - 1]);
    #pragma unroll
    for (int i = 0; i < 4; ++i) {
        const int g = base + i;
        if (g < E) offsets[g] = run;
        run += v[i];
    }
}

// ---------------- e1fill (fp16 LDS staging, 7 blocks/CU) --------------------
__launch_bounds__(256, 7)
__global__ void e1fill_kernel(const float* __restrict__ sbf, const float* __restrict__ w_sbf1,
                              const int* __restrict__ idx_ji, const int* __restrict__ idx_kj,
                              const int* __restrict__ rank, const int* __restrict__ offsets,
                              _Float16* __restrict__ E1p, int* __restrict__ kjp, int T)
{
    __shared__ _Float16 s_lds[256 * 44];
    const int tid = threadIdx.x;
    const long long t0 = (long long)blockIdx.x * 256;
    const int nrow = min(256, (int)(T - t0));
    const int nel  = nrow * 42;
    const float* base = sbf + t0 * 42;

    for (int i = tid * 4; i + 3 < nel; i += 1024) {
        const float4 v = *(const float4*)&base[i];
        s_lds[(i + 0) + 2 * ((i + 0) / 42)] = (_Float16)v.x;
        s_lds[(i + 1) + 2 * ((i + 1) / 42)] = (_Float16)v.y;
        s_lds[(i + 2) + 2 * ((i + 2) / 42)] = (_Float16)v.z;
        s_lds[(i + 3) + 2 * ((i + 3) / 42)] = (_Float16)v.w;
    }
    const int tail0 = nel & ~3;
    if (tid < nel - tail0) { const int g = tail0 + tid; s_lds[g + 2 * (g / 42)] = (_Float16)base[g]; }
    __syncthreads();

    const int t = (int)t0 + tid;
    if (t >= T) return;
    const _Float16* srow = &s_lds[tid * 44];
    float e1[8] = {0.f, 0.f, 0.f, 0.f, 0.f, 0.f, 0.f, 0.f};
    #pragma unroll
    for (int q = 0; q < 42; ++q) {
        const float s = (float)srow[q];
        #pragma unroll
        for (int p = 0; p < 8; ++p) e1[p] = fmaf(s, w_sbf1[q * 8 + p], e1[p]);
    }
    f16x8 eh;
    #pragma unroll
    for (int p = 0; p < 8; ++p) eh[p] = (_Float16)e1[p];
    const int ji  = idx_ji[t];
    const int pos = offsets[ji] + rank[t];
    *(f16x8*)&E1p[(size_t)pos * 8] = eh;
    kjp[pos] = idx_kj[t];
}

// ---------------- gather: fp16 E1 stream + fp16 xkjd table ------------------
__launch_bounds__(256, 4)
__global__ void gather_kernel(const _Float16* __restrict__ E1p, const int* __restrict__ kjp,
                              const float* __restrict__ w_sbf2, const int* __restrict__ offsets,
                              const _Float16* __restrict__ xkjd, float* __restrict__ agg, int E)
{
    const int tid  = threadIdx.x;
    const int lane = tid & 63;
    const int e    = blockIdx.x * 4 + (tid >> 6);

    float w2[8];
    #pragma unroll
    for (int p = 0; p < 8; ++p) w2[p] = w_sbf2[p * 64 + lane];

    if (e >= E) return;
    const int j0 = __builtin_amdgcn_readfirstlane(offsets[e]);
    const int j1 = __builtin_amdgcn_readfirstlane(offsets[e + 1]);

    float acc = 0.f;
    if (j0 < j1) {
        int kj = __builtin_amdgcn_readfirstlane(kjp[j0]);
        f16x8 ev = *(const f16x8*)&E1p[(size_t)j0 * 8];
        float xv = (float)xkjd[(size_t)kj * 64 + lane];
        for (int j = j0; j < j1; ++j) {
            float xn = 0.f; f16x8 evn = {};
            if (j + 1 < j1) {
                const int kn = __builtin_amdgcn_readfirstlane(kjp[j + 1]);
                evn = *(const f16x8*)&E1p[(size_t)(j + 1) * 8];
                xn  = (float)xkjd[(size_t)kn * 64 + lane];
            }
            float sv = (float)ev[0] * w2[0];
            sv = fmaf((float)ev[1], w2[1], sv);
            sv = fmaf((float)ev[2], w2[2], sv);
            sv = fmaf((float)ev[3], w2[3], sv);
            sv = fmaf((float)ev[4], w2[4], sv);
            sv = fmaf((float)ev[5], w2[5], sv);
            sv = fmaf((float)ev[6], w2[6], sv);
            sv = fmaf((float)ev[7], w2[7], sv);
            acc = fmaf(xv, sv, acc);
            ev = evn; xv = xn;
        }
    }
    agg[(size_t)e * 64 + lane] = acc;
}

// ---------------- K1: W3 = silu((silu(x@w_kj+b)*rbf_e)@w_down)  (fp16 out) --
__launch_bounds__(256, 4)
__global__ void k1_kernel(const float* __restrict__ x, const char* __restrict__ wkj_i,
                          const float* __restrict__ b_kj, const float* __restrict__ re1,
                          const float* __restrict__ w_rbf2, const char* __restrict__ wdn_i,
                          _Float16* __restrict__ W3, int E)
{
    __shared__ _Float16 slotA[4096], slotB[4096];
    __shared__ _Float16 t_lds[64 * TPH];
    __shared__ float w2_lds[8 * 128];
    const int tid = threadIdx.x, lane = tid & 63, wid = tid >> 6;
    const int acol = lane & 15, kq = lane >> 4;
    const int rowW = blockIdx.x * 64 + wid * 16;
    const int arow = rowW + acol;
    const bool av = arow < E;

    stage8k(wkj_i, slotA, lane, wid);
    const float* xr = x + (size_t)arow * 128;
    f16x8 aH[4], aL[4];
    #pragma unroll
    for (int ks = 0; ks < 4; ++ks) {
        f32x4 a0 = f32x4{0.f, 0.f, 0.f, 0.f}, a1 = f32x4{0.f, 0.f, 0.f, 0.f};
        if (av) { a0 = *(const f32x4*)&xr[ks * 32 + kq * 8];
                  a1 = *(const f32x4*)&xr[ks * 32 + kq * 8 + 4]; }
        split44h(a0, a1, aH[ks], aL[ks]);
    }
    float bv[8];
    #pragma unroll
    for (int n = 0; n < 8; ++n) bv[n] = b_kj[n * 16 + acol];
    f32x4 e1a[4], e1b[4];
    #pragma unroll
    for (int r = 0; r < 4; ++r) {
        const int ge = rowW + kq * 4 + r;
        e1a[r] = f32x4{0.f, 0.f, 0.f, 0.f}; e1b[r] = f32x4{0.f, 0.f, 0.f, 0.f};
        if (ge < E) { e1a[r] = *(const f32x4*)&re1[(size_t)ge * 8];
                      e1b[r] = *(const f32x4*)&re1[(size_t)ge * 8 + 4]; }
    }
    for (int i = tid; i < 1024; i += 256) w2_lds[i] = w_rbf2[i];
    __syncthreads();

    f32x4 acc[8];
    #pragma unroll
    for (int n = 0; n < 8; ++n) acc[n] = f32x4{0.f, 0.f, 0.f, 0.f};

    stage8k(wkj_i + 8192, slotB, lane, wid);
    mfma_ks<8>(aH[0], aL[0], slotA, acol, kq, acc); __syncthreads();
    stage8k(wkj_i + 16384, slotA, lane, wid);
    mfma_ks<8>(aH[1], aL[1], slotB, acol, kq, acc); __syncthreads();
    stage8k(wkj_i + 24576, slotB, lane, wid);
    mfma_ks<8>(aH[2], aL[2], slotA, acol, kq, acc); __syncthreads();
    stage4k(wdn_i, slotA, lane, wid);
    mfma_ks<8>(aH[3], aL[3], slotB, acol, kq, acc); __syncthreads();

    #pragma unroll
    for (int n = 0; n < 8; ++n) {
        const int c = n * 16 + acol;
        float w2c[8];
        #pragma unroll
        for (int p = 0; p < 8; ++p) w2c[p] = w2_lds[p * 128 + c];
        #pragma unroll
        for (int r = 0; r < 4; ++r) {
            float s = e1a[r][0] * w2c[0];
            s = fmaf(e1a[r][1], w2c[1], s);
            s = fmaf(e1a[r][2], w2c[2], s);
            s = fmaf(e1a[r][3], w2c[3], s);
            s = fmaf(e1b[r][0], w2c[4], s);
            s = fmaf(e1b[r][1], w2c[5], s);
            s = fmaf(e1b[r][2], w2c[6], s);
            s = fmaf(e1b[r][3], w2c[7], s);
            t_lds[(wid * 16 + kq * 4 + r) * TPH + c] = (_Float16)(silu_f(acc[n][r] + bv[n]) * s);
        }
    }
    __syncthreads();

    f32x4 acc2[4];
    #pragma unroll
    for (int n = 0; n < 4; ++n) acc2[n] = f32x4{0.f, 0.f, 0.f, 0.f};
    const int rb = (wid * 16 + acol) * TPH;

    f16x8 tH[4];
    #pragma unroll
    for (int q = 0; q < 4; ++q) tH[q] = tfrag16(t_lds, rb, q, kq);

    stage4k(wdn_i + 4096, slotB, lane, wid);
    mfma_ks1<4>(tH[0], slotA, acol, kq, acc2); __syncthreads();
    stage4k(wdn_i + 8192, slotA, lane, wid);
    mfma_ks1<4>(tH[1], slotB, acol, kq, acc2); __syncthreads();
    stage4k(wdn_i + 12288, slotB, lane, wid);
    mfma_ks1<4>(tH[2], slotA, acol, kq, acc2); __syncthreads();
    mfma_ks1<4>(tH[3], slotB, acol, kq, acc2);

    #pragma unroll
    for (int n = 0; n < 4; ++n) {
        const int c = n * 16 + acol;
        #pragma unroll
        for (int r = 0; r < 4; ++r) {
            const int ge = rowW + kq * 4 + r;
            if (ge < E) W3[(size_t)ge * 64 + c] = (_Float16)silu_f(acc2[n][r]);
        }
    }
}

// ---------------- kbig: h0 -> res1 -> w_bs+skip -> res2 -> res3 (9 GEMMs) ---
struct KBigArgs {
    const float* x; const float* W4; float* out;
    const char *wji, *wup, *r1w1, *r1w2, *wbs, *r2w1, *r2w2, *r3w1, *r3w2;
    const float *bji, *r1b1, *r1b2, *bbs, *r2b1, *r2b2, *r3b1, *r3b2;
    int E;
};

__launch_bounds__(256, 4)
__global__ void kbig_kernel(KBigArgs A_)
{
    __shared__ _Float16 slotA[4096], slotB[4096];
    __shared__ _Float16 t_lds[64 * TPH];
    const int tid = threadIdx.x, lane = tid & 63, wid = tid >> 6;
    const int acol = lane & 15, kq = lane >> 4;
    const int rowW = blockIdx.x * 64 + wid * 16;
    const int arow = rowW + acol;
    const int E = A_.E;
    const bool av = arow < E;
    const int rb = (wid * 16 + acol) * TPH;

    stage8k(A_.wji, slotA, lane, wid);

    const float* xr = A_.x + (size_t)arow * 128;
    const float* wr = A_.W4 + (size_t)arow * 64;
    f16x8 aH[4], aL[4], uH[2], uL[2];
    #pragma unroll
    for (int ks = 0; ks < 4; ++ks) {
        f32x4 a0 = f32x4{0.f, 0.f, 0.f, 0.f}, a1 = f32x4{0.f, 0.f, 0.f, 0.f};
        if (av) { a0 = *(const f32x4*)&xr[ks * 32 + kq * 8];
                  a1 = *(const f32x4*)&xr[ks * 32 + kq * 8 + 4]; }
        split44h(a0, a1, aH[ks], aL[ks]);
    }
    #pragma unroll
    for (int ks = 0; ks < 2; ++ks) {
        f32x4 u0 = f32x4{0.f, 0.f, 0.f, 0.f}, u1 = f32x4{0.f, 0.f, 0.f, 0.f};
        if (av) { u0 = *(const f32x4*)&wr[ks * 32 + kq * 8];
                  u1 = *(const f32x4*)&wr[ks * 32 + kq * 8 + 4]; }
        split44h(u0, u1, uH[ks], uL[ks]);
    }
    __syncthreads();

    f32x4 acc[8];
    #pragma unroll
    for (int n = 0; n < 8; ++n) acc[n] = f32x4{0.f, 0.f, 0.f, 0.f};

    // GEMM1: x @ w_ji  (2-pass)
    stage8k(A_.wji + 8192, slotB, lane, wid);
    mfma_ks<8>(aH[0], aL[0], slotA, acol, kq, acc); __syncthreads();
    stage8k(A_.wji + 16384, slotA, lane, wid);
    mfma_ks<8>(aH[1], aL[1], slotB, acol, kq, acc); __syncthreads();
    stage8k(A_.wji + 24576, slotB, lane, wid);
    mfma_ks<8>(aH[2], aL[2], slotA, acol, kq, acc); __syncthreads();
    stage8k(A_.wup, slotA, lane, wid);
    mfma_ks<8>(aH[3], aL[3], slotB, acol, kq, acc); __syncthreads();

    float res[8][4];
    #pragma unroll
    for (int n = 0; n < 8; ++n) {
        const float bv = A_.bji[n * 16 + acol];
        #pragma unroll
        for (int r = 0; r < 4; ++r) { res[n][r] = silu_f(acc[n][r] + bv); acc[n][r] = 0.f; }
    }

    // GEMM2: W4 @ w_up (K=64, 2-pass)
    stage8k(A_.wup + 8192, slotB, lane, wid);
    mfma_ks<8>(uH[0], uL[0], slotA, acol, kq, acc); __syncthreads();
    stage8k(A_.r1w1, slotA, lane, wid);
    mfma_ks<8>(uH[1], uL[1], slotB, acol, kq, acc); __syncthreads();

    #pragma unroll
    for (int n = 0; n < 8; ++n) {
        const int c = n * 16 + acol;
        #pragma unroll
        for (int r = 0; r < 4; ++r) {
            res[n][r] += silu_f(acc[n][r]);                     // h0
            t_lds[(wid * 16 + kq * 4 + r) * TPH + c] = (_Float16)res[n][r];
            acc[n][r] = 0.f;
        }
    }
    __syncthreads();

    // GEMM3: h0 @ r1w1 -> t1
    tgemm4h(A_.r1w1, A_.r1w2, slotA, slotB, t_lds, rb, kq, acol, lane, wid, acc);
    #pragma unroll
    for (int n = 0; n < 8; ++n) {
        const float bv = A_.r1b1[n * 16 + acol];
        const int c = n * 16 + acol;
        #pragma unroll
        for (int r = 0; r < 4; ++r) {
            t_lds[(wid * 16 + kq * 4 + r) * TPH + c] = (_Float16)silu_f(acc[n][r] + bv);
            acc[n][r] = 0.f;
        }
    }
    __syncthreads();

    // GEMM4: t1 @ r1w2 -> t2 = h0 + silu(.)
    tgemm4h(A_.r1w2, A_.wbs, slotA, slotB, t_lds, rb, kq, acol, lane, wid, acc);
    #pragma unroll
    for (int n = 0; n < 8; ++n) {
        const float bv = A_.r1b2[n * 16 + acol];
        const int c = n * 16 + acol;
        #pragma unroll
        for (int r = 0; r < 4; ++r) {
            t_lds[(wid * 16 + kq * 4 + r) * TPH + c] = (_Float16)(res[n][r] + silu_f(acc[n][r] + bv));
            acc[n][r] = 0.f;
        }
    }
    __syncthreads();

    // GEMM5: t2 @ w_bs -> h2 = silu(.) + x
    tgemm4h(A_.wbs, A_.r2w1, slotA, slotB, t_lds, rb, kq, acol, lane, wid, acc);
    #pragma unroll
    for (int n = 0; n < 8; ++n) {
        const float bv = A_.bbs[n * 16 + acol];
        const int c = n * 16 + acol;
        #pragma unroll
        for (int r = 0; r < 4; ++r) {
            const int ge = rowW + kq * 4 + r;
            const float xv = (ge < E) ? A_.x[(size_t)ge * 128 + c] : 0.f;
            res[n][r] = silu_f(acc[n][r] + bv) + xv;            // h2
            t_lds[(wid * 16 + kq * 4 + r) * TPH + c] = (_Float16)res[n][r];
            acc[n][r] = 0.f;
        }
    }
    __syncthreads();

    // GEMM6: h2 @ r2w1 -> t3
    tgemm4h(A_.r2w1, A_.r2w2, slotA, slotB, t_lds, rb, kq, acol, lane, wid, acc);
    #pragma unroll
    for (int n = 0; n < 8; ++n) {
        const float bv = A_.r2b1[n * 16 + acol];
        const int c = n * 16 + acol;
        #pragma unroll
        for (int r = 0; r < 4; ++r) {
            t_lds[(wid * 16 + kq * 4 + r) * TPH + c] = (_Float16)silu_f(acc[n][r] + bv);
            acc[n][r] = 0.f;
        }
    }
    __syncthreads();

    // GEMM7: t3 @ r2w2 -> h3 = h2 + silu(.)
    tgemm4h(A_.r2w2, A_.r3w1, slotA, slotB, t_lds, rb, kq, acol, lane, wid, acc);
    #pragma unroll
    for (int n = 0; n < 8; ++n) {
        const float bv = A_.r2b2[n * 16 + acol];
        const int c = n * 16 + acol;
        #pragma unroll
        for (int r = 0; r < 4; ++r) {
            res[n][r] += silu_f(acc[n][r] + bv);                // h3
            t_lds[(wid * 16 + kq * 4 + r) * TPH + c] = (_Float16)res[n][r];
            acc[n][r] = 0.f;
        }
    }
    __syncthreads();

    // GEMM8: h3 @ r3w1 -> t4
    tgemm4h(A_.r3w1, A_.r3w2, slotA, slotB, t_lds, rb, kq, acol, lane, wid, acc);
    #pragma unroll
    for (int n = 0; n < 8; ++n) {
        const float bv = A_.r3b1[n * 16 + acol];
        const int c = n * 16 + acol;
        #pragma unroll
        for (int r = 0; r < 4; ++r) {
            t_lds[(wid * 16 + kq * 4 + r) * TPH + c] = (_Float16)silu_f(acc[n][r] + bv);
            acc[n][r] = 0.f;
        }
    }
    __syncthreads();

    // GEMM9: t4 @ r3w2 -> out = h3 + silu(.)
    tgemm4h(A_.r3w2, nullptr, slotA, slotB, t_lds, rb, kq, acol, lane, wid, acc);
    #pragma unroll
    for (int n = 0; n < 8; ++n) {
        const float bv = A_.r3b2[n * 16 + acol];
        const int c = n * 16 + acol;
        #pragma unroll
        for (int r = 0; r < 4; ++r) {
            const int ge = rowW + kq * 4 + r;
            if (ge < E)
                A_.out[(size_t)ge * 128 + c] = res[n][r] + silu_f(acc[n][r] + bv);
        }
    }
}

// ---------------------------------------------------------------------------

extern "C" void kernel_launch(void* const* d_in, const int* in_sizes, int n_in,
                              void* d_out, int out_size, void* d_ws, size_t ws_size,
                              hipStream_t stream)
{
    const float* x      = (const float*)d_in[0];
    const float* rbf    = (const float*)d_in[1];
    const float* sbf    = (const float*)d_in[2];
    const int*   idx_kj = (const int*)d_in[3];
    const int*   idx_ji = (const int*)d_in[4];
    const float* w_rbf1 = (const float*)d_in[5];
    const float* w_rbf2 = (const float*)d_in[6];
    const float* w_sbf1 = (const float*)d_in[7];
    const float* w_sbf2 = (const float*)d_in[8];
    const float* w_kj   = (const float*)d_in[9];
    const float* b_kj   = (const float*)d_in[10];
    const float* w_ji   = (const float*)d_in[11];
    const float* b_ji   = (const float*)d_in[12];
    const float* w_down = (const float*)d_in[13];
    const float* w_up   = (const float*)d_in[14];
    const float* r1w1   = (const float*)d_in[15];
    const float* r1b1   = (const float*)d_in[16];
    const float* r1w2   = (const float*)d_in[17];
    const float* r1b2   = (const float*)d_in[18];
    const float* w_bs   = (const float*)d_in[19];
    const float* b_bs   = (const float*)d_in[20];
    const float* r2w1   = (const float*)d_in[21];
    const float* r2b1   = (const float*)d_in[22];
    const float* r2w2   = (const float*)d_in[23];
    const float* r2b2   = (const float*)d_in[24];
    const float* r3w1   = (const float*)d_in[25];
    const float* r3b1   = (const float*)d_in[26];
    const float* r3w2   = (const float*)d_in[27];
    const float* r3b2   = (const float*)d_in[28];

    const int E = in_sizes[0] / 128;
    const int T = in_sizes[2] / 42;

    float* OUT = (float*)d_out;
    _Float16* W3 = (_Float16*)((char*)d_ws + (size_t)E * 128 * 4);    // [E,64] fp16
    float* W4  = (float*)((char*)d_ws + (size_t)E * 128 * 4
                                      + (size_t)E * 64 * 4);          // [E,64] fp32

    int*   cnt      = (int*)d_ws;                            // [E]
    int*   offsets  = cnt + (E + 64);                        // [E+1]
    int*   partial  = offsets + (E + 64);                    // [<=1024]
    int*   blockoff = partial + 1024;                        // [<=1024]
    _Float16* E1p   = (_Float16*)((char*)d_ws + (4u << 20)); // [T,8] fp16  48 MB
    int*   kjp      = (int*)((char*)d_ws + (102u << 20));    // [T]     12 MB
    float* re1      = (float*)((char*)d_ws + (116u << 20));  // [E,8]  9.6 MB
    char*  wimg     = (char*)d_ws + (130u << 20);            // 320 KB fp16 images
    int*   rank     = (int*)((char*)d_ws + (134u << 20));    // [T]     12 MB

    char* wkj_i  = wimg;
    char* wji_i  = wimg + 32768;
    char* wdn_i  = wimg + 65536;    // 16 KB (128x64)
    char* wup_i  = wimg + 81920;    // 16 KB (64x128)
    char* r1w1_i = wimg + 98304;
    char* r1w2_i = wimg + 131072;
    char* wbs_i  = wimg + 163840;
    char* r2w1_i = wimg + 196608;
    char* r2w2_i = wimg + 229376;
    char* r3w1_i = wimg + 262144;
    char* r3w2_i = wimg + 294912;

    const dim3 b256(256);
    const int gB  = (E + 63) / 64;
    const int gT  = (T + 255) / 256;
    const int gT4 = (T + 1023) / 1024;
    const int NB  = (E + 1023) / 1024;
    const int gE4 = (E + 3) / 4;
    const int gR  = (E * 8 + 255) / 256;

    ProArgs P;
    P.w[0]  = {w_kj,   wkj_i,  128, 128};
    P.w[1]  = {w_ji,   wji_i,  128, 128};
    P.w[2]  = {w_down, wdn_i,  128,  64};
    P.w[3]  = {w_up,   wup_i,   64, 128};
    P.w[4]  = {r1w1,   r1w1_i, 128, 128};
    P.w[5]  = {r1w2,   r1w2_i, 128, 128};
    P.w[6]  = {w_bs,   wbs_i,  128, 128};
    P.w[7]  = {r2w1,   r2w1_i, 128, 128};
    P.w[8]  = {r2w2,   r2w2_i, 128, 128};
    P.w[9]  = {r3w1,   r3w1_i, 128, 128};
    P.w[10] = {r3w2,   r3w2_i, 128, 128};
    P.rbf = rbf; P.w_rbf1 = w_rbf1; P.re1 = re1; P.E = E;
    P.idx_ji = idx_ji; P.cnt = cnt; P.rank = rank; P.T = T;
    P.nW = 44; P.nR = gR;

    hipMemsetAsync(cnt, 0, (size_t)E * 4, stream);
    pro_kernel<<<44 + gR + gT4, b256, 0, stream>>>(P);
    scan_partial_kernel<<<NB, b256, 0, stream>>>(cnt, partial, E);
    scan_block_kernel<<<1, b256, 0, stream>>>(partial, blockoff, NB, offsets, E);
    scan_final_kernel<<<NB, b256, 0, stream>>>(cnt, blockoff, offsets, E);
    e1fill_kernel<<<gT, b256, 0, stream>>>(sbf, w_sbf1, idx_ji, idx_kj, rank, offsets, E1p, kjp, T);

    k1_kernel<<<gB, b256, 0, stream>>>(x, wkj_i, b_kj, re1, w_rbf2, wdn_i, W3, E);
    gather_kernel<<<gE4, b256, 0, stream>>>(E1p, kjp, w_sbf2, offsets, W3, W4, E);

    KBigArgs ka;
    ka.x = x; ka.W4 = W4; ka.out = OUT;
    ka.wji = wji_i; ka.wup = wup_i; ka.r1w1 = r1w1_i; ka.r1w2 = r1w2_i; ka.wbs = wbs_i;
    ka.r2w1 = r2w1_i; ka.r2w2 = r2w2_i; ka.r3w1 = r3w1_i; ka.r3w2 = r3w2_i;
    ka.bji = b_ji; ka.r1b1 = r1b1; ka.r1b2 = r1b2; ka.bbs = b_bs;
    ka.r2b1 = r2b1; ka.r2b2 = r2b2; ka.r3b1 = r3b1; ka.r3b2 = r3b2;
    ka.E = E;
    kbig_kernel<<<gB, b256, 0, stream>>>(ka);
}

// Round 22
// 1003.065 us; speedup vs baseline: 1.1784x; 1.1784x over previous
//
#include <hip/hip_runtime.h>
#include <hip/hip_bf16.h>

// ---------------------------------------------------------------------------
// DimeNet++ interaction block, round 22:
//   Round-21 (fp16 t_lds, 1-pass GEMMs 3..9) with the spill bug fixed:
//   __launch_bounds__(256,3) on kbig/k1 (r21's (256,4) capped VGPR at 64 ->
//   register spill -> 762 MB scratch writes, kbig 310->495). LDS stays
//   33.8 KB so hardware may still exceed 3 blocks/CU without the hard cap.
// ---------------------------------------------------------------------------

typedef __attribute__((ext_vector_type(8))) _Float16 f16x8;
typedef __attribute__((ext_vector_type(4))) float f32x4;

__device__ __forceinline__ float silu_f(float v) {
    return v * __builtin_amdgcn_rcpf(1.0f + __expf(-v));
}

__device__ __forceinline__ void split44h(f32x4 a, f32x4 b, f16x8& hi, f16x8& lo) {
    float f[8] = {a[0], a[1], a[2], a[3], b[0], b[1], b[2], b[3]};
    #pragma unroll
    for (int j = 0; j < 8; ++j) {
        const _Float16 h = (_Float16)f[j];
        hi[j] = h;
        lo[j] = (_Float16)(f[j] - (float)h);
    }
}

__device__ __forceinline__ void gll16(const void* g, void* l) {
    __builtin_amdgcn_global_load_lds((const __attribute__((address_space(1))) void*)g,
                                     (__attribute__((address_space(3))) void*)l, 16, 0, 0);
}
__device__ __forceinline__ void stage8k(const char* g, _Float16* l, int lane, int wid) {
    #pragma unroll
    for (int i = 0; i < 2; ++i) {
        const int off = ((i * 4 + wid) << 10);
        gll16(g + off + lane * 16, (char*)l + off);
    }
}
__device__ __forceinline__ void stage4k(const char* g, _Float16* l, int lane, int wid) {
    const int off = (wid << 10);
    gll16(g + off + lane * 16, (char*)l + off);
}

// 2-pass split-fp16 MFMA (A = fp32 registers split hi/lo)
template<int NF>
__device__ __forceinline__ void mfma_ks(f16x8 ah, f16x8 al, const _Float16* slot,
                                        int acol, int kq, f32x4* acc) {
    #pragma unroll
    for (int n = 0; n < NF; ++n) {
        const int c = n * 16 + acol;
        const int sw = (kq ^ ((c >> 1) & 3)) << 3;
        const f16x8 bh = *(const f16x8*)&slot[c * 32 + sw];
        acc[n] = __builtin_amdgcn_mfma_f32_16x16x32_f16(ah, bh, acc[n], 0, 0, 0);
        acc[n] = __builtin_amdgcn_mfma_f32_16x16x32_f16(al, bh, acc[n], 0, 0, 0);
    }
}

// 1-pass fp16 MFMA (A already fp16)
template<int NF>
__device__ __forceinline__ void mfma_ks1(f16x8 ah, const _Float16* slot,
                                         int acol, int kq, f32x4* acc) {
    #pragma unroll
    for (int n = 0; n < NF; ++n) {
        const int c = n * 16 + acol;
        const int sw = (kq ^ ((c >> 1) & 3)) << 3;
        const f16x8 bh = *(const f16x8*)&slot[c * 32 + sw];
        acc[n] = __builtin_amdgcn_mfma_f32_16x16x32_f16(ah, bh, acc[n], 0, 0, 0);
    }
}

#define TPH 136   // fp16 t_lds pitch in halves (16B-aligned frags, 2-way banks)

__device__ __forceinline__ f16x8 tfrag16(const _Float16* tl, int rb, int q, int kq) {
    return *(const f16x8*)&tl[rb + q * 32 + kq * 8];
}

// 4-phase 128-k GEMM, A = fp16 t_lds (1-pass), B LDS double-buffered
__device__ __forceinline__ void tgemm4h(const char* img, const char* imgnext,
                                        _Float16* sA, _Float16* sB,
                                        const _Float16* tl, int rb,
                                        int kq, int acol, int lane, int wid, f32x4* acc)
{
    f16x8 Ah[4];
    #pragma unroll
    for (int q = 0; q < 4; ++q) Ah[q] = tfrag16(tl, rb, q, kq);

    stage8k(img + 8192, sB, lane, wid);
    mfma_ks1<8>(Ah[0], sA, acol, kq, acc); __syncthreads();
    stage8k(img + 16384, sA, lane, wid);
    mfma_ks1<8>(Ah[1], sB, acol, kq, acc); __syncthreads();
    stage8k(img + 24576, sB, lane, wid);
    mfma_ks1<8>(Ah[2], sA, acol, kq, acc); __syncthreads();
    if (imgnext) stage8k(imgnext, sA, lane, wid);
    mfma_ks1<8>(Ah[3], sB, acol, kq, acc); __syncthreads();
}

// ---------------- fused prologue: wprep | rbf1 | count_rank -----------------
struct WDesc { const float* src; char* dst; int K; int N; };
struct ProArgs {
    WDesc w[11];
    const float* rbf; const float* w_rbf1; float* re1; int E;
    const int* idx_ji; int* cnt; int* rank; int T;
    int nW, nR;
};

__device__ void wprep_body(const ProArgs& P, int b) {
    const WDesc d = P.w[b >> 2];
    const int h = b & 3;
    if (h * 32 >= d.K) return;
    char* slab = d.dst + (size_t)h * d.N * 64;
    for (int idx = threadIdx.x; idx < d.N * 4; idx += 256) {
        const int c = idx >> 2, ch = idx & 3;
        f16x8 v;
        #pragma unroll
        for (int j = 0; j < 8; ++j)
            v[j] = (_Float16)d.src[(size_t)(h * 32 + ch * 8 + j) * d.N + c];
        *(f16x8*)(slab + c * 64 + ((ch ^ ((c >> 1) & 3)) << 4)) = v;
    }
}

__device__ void rbf1_body(const ProArgs& P, int b) {
    const int i = b * 256 + threadIdx.x;
    const int e = i >> 3, p = i & 7;
    if (e < P.E) {
        float s = 0.f;
        #pragma unroll
        for (int q = 0; q < 6; ++q) s = fmaf(P.rbf[e * 6 + q], P.w_rbf1[q * 8 + p], s);
        P.re1[i] = s;
    }
}

__device__ void count_rank_body(const ProArgs& P, int b) {
    const int i = (b * 256 + threadIdx.x) * 4;
    const int T = P.T;
    if (i + 3 < T) {
        const int4 j = *(const int4*)&P.idx_ji[i];
        int4 r;
        r.x = atomicAdd(&P.cnt[j.x], 1);
        r.y = atomicAdd(&P.cnt[j.y], 1);
        r.z = atomicAdd(&P.cnt[j.z], 1);
        r.w = atomicAdd(&P.cnt[j.w], 1);
        *(int4*)&P.rank[i] = r;
    } else {
        for (int k = i; k < T; ++k) P.rank[k] = atomicAdd(&P.cnt[P.idx_ji[k]], 1);
    }
}

__global__ void pro_kernel(ProArgs P) {
    const int b = blockIdx.x;
    if (b < P.nW)             wprep_body(P, b);
    else if (b < P.nW + P.nR) rbf1_body(P, b - P.nW);
    else                      count_rank_body(P, b - P.nW - P.nR);
}

// ---------------- scans ------------------------------------------------------

__global__ void scan_partial_kernel(const int* __restrict__ cnt, int* __restrict__ partial, int E) {
    __shared__ int red[256];
    const int tid = threadIdx.x;
    const int base = blockIdx.x * 1024 + tid * 4;
    int s = 0;
    #pragma unroll
    for (int i = 0; i < 4; ++i) { const int g = base + i; if (g < E) s += cnt[g]; }
    red[tid] = s;
    __syncthreads();
    for (int off = 128; off > 0; off >>= 1) {
        if (tid < off) red[tid] += red[tid + off];
        __syncthreads();
    }
    if (tid == 0) partial[blockIdx.x] = red[0];
}

__global__ void scan_block_kernel(const int* __restrict__ partial, int* __restrict__ blockoff,
                                  int NB, int* offsets, int E) {
    __shared__ int red[256];
    const int tid = threadIdx.x;
    int v[4]; int s = 0;
    #pragma unroll
    for (int i = 0; i < 4; ++i) { const int g = tid * 4 + i; v[i] = (g < NB) ? partial[g] : 0; s += v[i]; }
    red[tid] = s;
    __syncthreads();
    for (int off = 1; off < 256; off <<= 1) {
        const int add = (tid >= off) ? red[tid - off] : 0;
        __syncthreads();
        red[tid] += add;
        __syncthreads();
    }
    int excl = (tid == 0) ? 0 : red[tid - 1];
    #pragma unroll
    for (int i = 0; i < 4; ++i) { const int g = tid * 4 + i; if (g < NB) blockoff[g] = excl; excl += v[i]; }
    if (tid == 255) offsets[E] = red[255];
}

__global__ void scan_final_kernel(const int* __restrict__ cnt, const int* __restrict__ blockoff,
                                  int* __restrict__ offsets, int E) {
    __shared__ int red[256];
    const int tid = threadIdx.x;
    const int base = blockIdx.x * 1024 + tid * 4;
    int v[4]; int s = 0;
    #pragma unroll
    for (int i = 0; i < 4; ++i) { const int g = base + i; v[i] = (g < E) ? cnt[g] : 0; s += v[i]; }
    red[tid] = s;
    __syncthreads();
    for (int off = 1; off < 256; off <<= 1) {
        const int add = (tid >= off) ? red[tid - off] : 0;
        __syncthreads();
        red[tid] += add;
        __syncthreads();
    }
    int run = blockoff[blockIdx.x] + ((tid == 0) ? 0 : red[tid - 1]);
    #pragma unroll
    for (int i = 0; i < 4; ++i) {
        const int g = base + i;
        if (g < E) offsets[g] = run;
        run += v[i];
    }
}

// ---------------- e1fill (fp16 LDS staging, 7 blocks/CU) --------------------
__launch_bounds__(256, 7)
__global__ void e1fill_kernel(const float* __restrict__ sbf, const float* __restrict__ w_sbf1,
                              const int* __restrict__ idx_ji, const int* __restrict__ idx_kj,
                              const int* __restrict__ rank, const int* __restrict__ offsets,
                              _Float16* __restrict__ E1p, int* __restrict__ kjp, int T)
{
    __shared__ _Float16 s_lds[256 * 44];
    const int tid = threadIdx.x;
    const long long t0 = (long long)blockIdx.x * 256;
    const int nrow = min(256, (int)(T - t0));
    const int nel  = nrow * 42;
    const float* base = sbf + t0 * 42;

    for (int i = tid * 4; i + 3 < nel; i += 1024) {
        const float4 v = *(const float4*)&base[i];
        s_lds[(i + 0) + 2 * ((i + 0) / 42)] = (_Float16)v.x;
        s_lds[(i + 1) + 2 * ((i + 1) / 42)] = (_Float16)v.y;
        s_lds[(i + 2) + 2 * ((i + 2) / 42)] = (_Float16)v.z;
        s_lds[(i + 3) + 2 * ((i + 3) / 42)] = (_Float16)v.w;
    }
    const int tail0 = nel & ~3;
    if (tid < nel - tail0) { const int g = tail0 + tid; s_lds[g + 2 * (g / 42)] = (_Float16)base[g]; }
    __syncthreads();

    const int t = (int)t0 + tid;
    if (t >= T) return;
    const _Float16* srow = &s_lds[tid * 44];
    float e1[8] = {0.f, 0.f, 0.f, 0.f, 0.f, 0.f, 0.f, 0.f};
    #pragma unroll
    for (int q = 0; q < 42; ++q) {
        const float s = (float)srow[q];
        #pragma unroll
        for (int p = 0; p < 8; ++p) e1[p] = fmaf(s, w_sbf1[q * 8 + p], e1[p]);
    }
    f16x8 eh;
    #pragma unroll
    for (int p = 0; p < 8; ++p) eh[p] = (_Float16)e1[p];
    const int ji  = idx_ji[t];
    const int pos = offsets[ji] + rank[t];
    *(f16x8*)&E1p[(size_t)pos * 8] = eh;
    kjp[pos] = idx_kj[t];
}

// ---------------- gather: fp16 E1 stream + fp16 xkjd table ------------------
__launch_bounds__(256, 4)
__global__ void gather_kernel(const _Float16* __restrict__ E1p, const int* __restrict__ kjp,
                              const float* __restrict__ w_sbf2, const int* __restrict__ offsets,
                              const _Float16* __restrict__ xkjd, float* __restrict__ agg, int E)
{
    const int tid  = threadIdx.x;
    const int lane = tid & 63;
    const int e    = blockIdx.x * 4 + (tid >> 6);

    float w2[8];
    #pragma unroll
    for (int p = 0; p < 8; ++p) w2[p] = w_sbf2[p * 64 + lane];

    if (e >= E) return;
    const int j0 = __builtin_amdgcn_readfirstlane(offsets[e]);
    const int j1 = __builtin_amdgcn_readfirstlane(offsets[e + 1]);

    float acc = 0.f;
    if (j0 < j1) {
        int kj = __builtin_amdgcn_readfirstlane(kjp[j0]);
        f16x8 ev = *(const f16x8*)&E1p[(size_t)j0 * 8];
        float xv = (float)xkjd[(size_t)kj * 64 + lane];
        for (int j = j0; j < j1; ++j) {
            float xn = 0.f; f16x8 evn = {};
            if (j + 1 < j1) {
                const int kn = __builtin_amdgcn_readfirstlane(kjp[j + 1]);
                evn = *(const f16x8*)&E1p[(size_t)(j + 1) * 8];
                xn  = (float)xkjd[(size_t)kn * 64 + lane];
            }
            float sv = (float)ev[0] * w2[0];
            sv = fmaf((float)ev[1], w2[1], sv);
            sv = fmaf((float)ev[2], w2[2], sv);
            sv = fmaf((float)ev[3], w2[3], sv);
            sv = fmaf((float)ev[4], w2[4], sv);
            sv = fmaf((float)ev[5], w2[5], sv);
            sv = fmaf((float)ev[6], w2[6], sv);
            sv = fmaf((float)ev[7], w2[7], sv);
            acc = fmaf(xv, sv, acc);
            ev = evn; xv = xn;
        }
    }
    agg[(size_t)e * 64 + lane] = acc;
}

// ---------------- K1: W3 = silu((silu(x@w_kj+b)*rbf_e)@w_down)  (fp16 out) --
__launch_bounds__(256, 3)
__global__ void k1_kernel(const float* __restrict__ x, const char* __restrict__ wkj_i,
                          const float* __restrict__ b_kj, const float* __restrict__ re1,
                          const float* __restrict__ w_rbf2, const char* __restrict__ wdn_i,
                          _Float16* __restrict__ W3, int E)
{
    __shared__ _Float16 slotA[4096], slotB[4096];
    __shared__ _Float16 t_lds[64 * TPH];
    __shared__ float w2_lds[8 * 128];
    const int tid = threadIdx.x, lane = tid & 63, wid = tid >> 6;
    const int acol = lane & 15, kq = lane >> 4;
    const int rowW = blockIdx.x * 64 + wid * 16;
    const int arow = rowW + acol;
    const bool av = arow < E;

    stage8k(wkj_i, slotA, lane, wid);
    const float* xr = x + (size_t)arow * 128;
    f16x8 aH[4], aL[4];
    #pragma unroll
    for (int ks = 0; ks < 4; ++ks) {
        f32x4 a0 = f32x4{0.f, 0.f, 0.f, 0.f}, a1 = f32x4{0.f, 0.f, 0.f, 0.f};
        if (av) { a0 = *(const f32x4*)&xr[ks * 32 + kq * 8];
                  a1 = *(const f32x4*)&xr[ks * 32 + kq * 8 + 4]; }
        split44h(a0, a1, aH[ks], aL[ks]);
    }
    float bv[8];
    #pragma unroll
    for (int n = 0; n < 8; ++n) bv[n] = b_kj[n * 16 + acol];
    f32x4 e1a[4], e1b[4];
    #pragma unroll
    for (int r = 0; r < 4; ++r) {
        const int ge = rowW + kq * 4 + r;
        e1a[r] = f32x4{0.f, 0.f, 0.f, 0.f}; e1b[r] = f32x4{0.f, 0.f, 0.f, 0.f};
        if (ge < E) { e1a[r] = *(const f32x4*)&re1[(size_t)ge * 8];
                      e1b[r] = *(const f32x4*)&re1[(size_t)ge * 8 + 4]; }
    }
    for (int i = tid; i < 1024; i += 256) w2_lds[i] = w_rbf2[i];
    __syncthreads();

    f32x4 acc[8];
    #pragma unroll
    for (int n = 0; n < 8; ++n) acc[n] = f32x4{0.f, 0.f, 0.f, 0.f};

    stage8k(wkj_i + 8192, slotB, lane, wid);
    mfma_ks<8>(aH[0], aL[0], slotA, acol, kq, acc); __syncthreads();
    stage8k(wkj_i + 16384, slotA, lane, wid);
    mfma_ks<8>(aH[1], aL[1], slotB, acol, kq, acc); __syncthreads();
    stage8k(wkj_i + 24576, slotB, lane, wid);
    mfma_ks<8>(aH[2], aL[2], slotA, acol, kq, acc); __syncthreads();
    stage4k(wdn_i, slotA, lane, wid);
    mfma_ks<8>(aH[3], aL[3], slotB, acol, kq, acc); __syncthreads();

    #pragma unroll
    for (int n = 0; n < 8; ++n) {
        const int c = n * 16 + acol;
        float w2c[8];
        #pragma unroll
        for (int p = 0; p < 8; ++p) w2c[p] = w2_lds[p * 128 + c];
        #pragma unroll
        for (int r = 0; r < 4; ++r) {
            float s = e1a[r][0] * w2c[0];
            s = fmaf(e1a[r][1], w2c[1], s);
            s = fmaf(e1a[r][2], w2c[2], s);
            s = fmaf(e1a[r][3], w2c[3], s);
            s = fmaf(e1b[r][0], w2c[4], s);
            s = fmaf(e1b[r][1], w2c[5], s);
            s = fmaf(e1b[r][2], w2c[6], s);
            s = fmaf(e1b[r][3], w2c[7], s);
            t_lds[(wid * 16 + kq * 4 + r) * TPH + c] = (_Float16)(silu_f(acc[n][r] + bv[n]) * s);
        }
    }
    __syncthreads();

    f32x4 acc2[4];
    #pragma unroll
    for (int n = 0; n < 4; ++n) acc2[n] = f32x4{0.f, 0.f, 0.f, 0.f};
    const int rb = (wid * 16 + acol) * TPH;

    f16x8 tH[4];
    #pragma unroll
    for (int q = 0; q < 4; ++q) tH[q] = tfrag16(t_lds, rb, q, kq);

    stage4k(wdn_i + 4096, slotB, lane, wid);
    mfma_ks1<4>(tH[0], slotA, acol, kq, acc2); __syncthreads();
    stage4k(wdn_i + 8192, slotA, lane, wid);
    mfma_ks1<4>(tH[1], slotB, acol, kq, acc2); __syncthreads();
    stage4k(wdn_i + 12288, slotB, lane, wid);
    mfma_ks1<4>(tH[2], slotA, acol, kq, acc2); __syncthreads();
    mfma_ks1<4>(tH[3], slotB, acol, kq, acc2);

    #pragma unroll
    for (int n = 0; n < 4; ++n) {
        const int c = n * 16 + acol;
        #pragma unroll
        for (int r = 0; r < 4; ++r) {
            const int ge = rowW + kq * 4 + r;
            if (ge < E) W3[(size_t)ge * 64 + c] = (_Float16)silu_f(acc2[n][r]);
        }
    }
}

// ---------------- kbig: h0 -> res1 -> w_bs+skip -> res2 -> res3 (9 GEMMs) ---
struct KBigArgs {
    const float* x; const float* W4; float* out;
    const char *wji, *wup, *r1w1, *r1w2, *wbs, *r2w1, *r2w2, *r3w1, *r3w2;
    const float *bji, *r1b1, *r1b2, *bbs, *r2b1, *r2b2, *r3b1, *r3b2;
    int E;
};

__launch_bounds__(256, 3)
__global__ void kbig_kernel(KBigArgs A_)
{
    __shared__ _Float16 slotA[4096], slotB[4096];
    __shared__ _Float16 t_lds[64 * TPH];
    const int tid = threadIdx.x, lane = tid & 63, wid = tid >> 6;
    const int acol = lane & 15, kq = lane >> 4;
    const int rowW = blockIdx.x * 64 + wid * 16;
    const int arow = rowW + acol;
    const int E = A_.E;
    const bool av = arow < E;
    const int rb = (wid * 16 + acol) * TPH;

    stage8k(A_.wji, slotA, lane, wid);

    const float* xr = A_.x + (size_t)arow * 128;
    const float* wr = A_.W4 + (size_t)arow * 64;
    f16x8 aH[4], aL[4], uH[2], uL[2];
    #pragma unroll
    for (int ks = 0; ks < 4; ++ks) {
        f32x4 a0 = f32x4{0.f, 0.f, 0.f, 0.f}, a1 = f32x4{0.f, 0.f, 0.f, 0.f};
        if (av) { a0 = *(const f32x4*)&xr[ks * 32 + kq * 8];
                  a1 = *(const f32x4*)&xr[ks * 32 + kq * 8 + 4]; }
        split44h(a0, a1, aH[ks], aL[ks]);
    }
    #pragma unroll
    for (int ks = 0; ks < 2; ++ks) {
        f32x4 u0 = f32x4{0.f, 0.f, 0.f, 0.f}, u1 = f32x4{0.f, 0.f, 0.f, 0.f};
        if (av) { u0 = *(const f32x4*)&wr[ks * 32 + kq * 8];
                  u1 = *(const f32x4*)&wr[ks * 32 + kq * 8 + 4]; }
        split44h(u0, u1, uH[ks], uL[ks]);
    }
    __syncthreads();

    f32x4 acc[8];
    #pragma unroll
    for (int n = 0; n < 8; ++n) acc[n] = f32x4{0.f, 0.f, 0.f, 0.f};

    // GEMM1: x @ w_ji  (2-pass)
    stage8k(A_.wji + 8192, slotB, lane, wid);
    mfma_ks<8>(aH[0], aL[0], slotA, acol, kq, acc); __syncthreads();
    stage8k(A_.wji + 16384, slotA, lane, wid);
    mfma_ks<8>(aH[1], aL[1], slotB, acol, kq, acc); __syncthreads();
    stage8k(A_.wji + 24576, slotB, lane, wid);
    mfma_ks<8>(aH[2], aL[2], slotA, acol, kq, acc); __syncthreads();
    stage8k(A_.wup, slotA, lane, wid);
    mfma_ks<8>(aH[3], aL[3], slotB, acol, kq, acc); __syncthreads();

    float res[8][4];
    #pragma unroll
    for (int n = 0; n < 8; ++n) {
        const float bv = A_.bji[n * 16 + acol];
        #pragma unroll
        for (int r = 0; r < 4; ++r) { res[n][r] = silu_f(acc[n][r] + bv); acc[n][r] = 0.f; }
    }

    // GEMM2: W4 @ w_up (K=64, 2-pass)
    stage8k(A_.wup + 8192, slotB, lane, wid);
    mfma_ks<8>(uH[0], uL[0], slotA, acol, kq, acc); __syncthreads();
    stage8k(A_.r1w1, slotA, lane, wid);
    mfma_ks<8>(uH[1], uL[1], slotB, acol, kq, acc); __syncthreads();

    #pragma unroll
    for (int n = 0; n < 8; ++n) {
        const int c = n * 16 + acol;
        #pragma unroll
        for (int r = 0; r < 4; ++r) {
            res[n][r] += silu_f(acc[n][r]);                     // h0
            t_lds[(wid * 16 + kq * 4 + r) * TPH + c] = (_Float16)res[n][r];
            acc[n][r] = 0.f;
        }
    }
    __syncthreads();

    // GEMM3: h0 @ r1w1 -> t1
    tgemm4h(A_.r1w1, A_.r1w2, slotA, slotB, t_lds, rb, kq, acol, lane, wid, acc);
    #pragma unroll
    for (int n = 0; n < 8; ++n) {
        const float bv = A_.r1b1[n * 16 + acol];
        const int c = n * 16 + acol;
        #pragma unroll
        for (int r = 0; r < 4; ++r) {
            t_lds[(wid * 16 + kq * 4 + r) * TPH + c] = (_Float16)silu_f(acc[n][r] + bv);
            acc[n][r] = 0.f;
        }
    }
    __syncthreads();

    // GEMM4: t1 @ r1w2 -> t2 = h0 + silu(.)
    tgemm4h(A_.r1w2, A_.wbs, slotA, slotB, t_lds, rb, kq, acol, lane, wid, acc);
    #pragma unroll
    for (int n = 0; n < 8; ++n) {
        const float bv = A_.r1b2[n * 16 + acol];
        const int c = n * 16 + acol;
        #pragma unroll
        for (int r = 0; r < 4; ++r) {
            t_lds[(wid * 16 + kq * 4 + r) * TPH + c] = (_Float16)(res[n][r] + silu_f(acc[n][r] + bv));
            acc[n][r] = 0.f;
        }
    }
    __syncthreads();

    // GEMM5: t2 @ w_bs -> h2 = silu(.) + x
    tgemm4h(A_.wbs, A_.r2w1, slotA, slotB, t_lds, rb, kq, acol, lane, wid, acc);
    #pragma unroll
    for (int n = 0; n < 8; ++n) {
        const float bv = A_.bbs[n * 16 + acol];
        const int c = n * 16 + acol;
        #pragma unroll
        for (int r = 0; r < 4; ++r) {
            const int ge = rowW + kq * 4 + r;
            const float xv = (ge < E) ? A_.x[(size_t)ge * 128 + c] : 0.f;
            res[n][r] = silu_f(acc[n][r] + bv) + xv;            // h2
            t_lds[(wid * 16 + kq * 4 + r) * TPH + c] = (_Float16)res[n][r];
            acc[n][r] = 0.f;
        }
    }
    __syncthreads();

    // GEMM6: h2 @ r2w1 -> t3
    tgemm4h(A_.r2w1, A_.r2w2, slotA, slotB, t_lds, rb, kq, acol, lane, wid, acc);
    #pragma unroll
    for (int n = 0; n < 8; ++n) {
        const float bv = A_.r2b1[n * 16 + acol];
        const int c = n * 16 + acol;
        #pragma unroll
        for (int r = 0; r < 4; ++r) {
            t_lds[(wid * 16 + kq * 4 + r) * TPH + c] = (_Float16)silu_f(acc[n][r] + bv);
            acc[n][r] = 0.f;
        }
    }
    __syncthreads();

    // GEMM7: t3 @ r2w2 -> h3 = h2 + silu(.)
    tgemm4h(A_.r2w2, A_.r3w1, slotA, slotB, t_lds, rb, kq, acol, lane, wid, acc);
    #pragma unroll
    for (int n = 0; n < 8; ++n) {
        const float bv = A_.r2b2[n * 16 + acol];
        const int c = n * 16 + acol;
        #pragma unroll
        for (int r = 0; r < 4; ++r) {
            res[n][r] += silu_f(acc[n][r] + bv);                // h3
            t_lds[(wid * 16 + kq * 4 + r) * TPH + c] = (_Float16)res[n][r];
            acc[n][r] = 0.f;
        }
    }
    __syncthreads();

    // GEMM8: h3 @ r3w1 -> t4
    tgemm4h(A_.r3w1, A_.r3w2, slotA, slotB, t_lds, rb, kq, acol, lane, wid, acc);
    #pragma unroll
    for (int n = 0; n < 8; ++n) {
        const float bv = A_.r3b1[n * 16 + acol];
        const int c = n * 16 + acol;
        #pragma unroll
        for (int r = 0; r < 4; ++r) {
            t_lds[(wid * 16 + kq * 4 + r) * TPH + c] = (_Float16)silu_f(acc[n][r] + bv);
            acc[n][r] = 0.f;
        }
    }
    __syncthreads();

    // GEMM9: t4 @ r3w2 -> out = h3 + silu(.)
    tgemm4h(A_.r3w2, nullptr, slotA, slotB, t_lds, rb, kq, acol, lane, wid, acc);
    #pragma unroll
    for (int n = 0; n < 8; ++n) {
        const float bv = A_.r3b2[n * 16 + acol];
        const int c = n * 16 + acol;
        #pragma unroll
        for (int r = 0; r < 4; ++r) {
            const int ge = rowW + kq * 4 + r;
            if (ge < E)
                A_.out[(size_t)ge * 128 + c] = res[n][r] + silu_f(acc[n][r] + bv);
        }
    }
}

// ---------------------------------------------------------------------------

extern "C" void kernel_launch(void* const* d_in, const int* in_sizes, int n_in,
                              void* d_out, int out_size, void* d_ws, size_t ws_size,
                              hipStream_t stream)
{
    const float* x      = (const float*)d_in[0];
    const float* rbf    = (const float*)d_in[1];
    const float* sbf    = (const float*)d_in[2];
    const int*   idx_kj = (const int*)d_in[3];
    const int*   idx_ji = (const int*)d_in[4];
    const float* w_rbf1 = (const float*)d_in[5];
    const float* w_rbf2 = (const float*)d_in[6];
    const float* w_sbf1 = (const float*)d_in[7];
    const float* w_sbf2 = (const float*)d_in[8];
    const float* w_kj   = (const float*)d_in[9];
    const float* b_kj   = (const float*)d_in[10];
    const float* w_ji   = (const float*)d_in[11];
    const float* b_ji   = (const float*)d_in[12];
    const float* w_down = (const float*)d_in[13];
    const float* w_up   = (const float*)d_in[14];
    const float* r1w1   = (const float*)d_in[15];
    const float* r1b1   = (const float*)d_in[16];
    const float* r1w2   = (const float*)d_in[17];
    const float* r1b2   = (const float*)d_in[18];
    const float* w_bs   = (const float*)d_in[19];
    const float* b_bs   = (const float*)d_in[20];
    const float* r2w1   = (const float*)d_in[21];
    const float* r2b1   = (const float*)d_in[22];
    const float* r2w2   = (const float*)d_in[23];
    const float* r2b2   = (const float*)d_in[24];
    const float* r3w1   = (const float*)d_in[25];
    const float* r3b1   = (const float*)d_in[26];
    const float* r3w2   = (const float*)d_in[27];
    const float* r3b2   = (const float*)d_in[28];

    const int E = in_sizes[0] / 128;
    const int T = in_sizes[2] / 42;

    float* OUT = (float*)d_out;
    _Float16* W3 = (_Float16*)((char*)d_ws + (size_t)E * 128 * 4);    // [E,64] fp16
    float* W4  = (float*)((char*)d_ws + (size_t)E * 128 * 4
                                      + (size_t)E * 64 * 4);          // [E,64] fp32

    int*   cnt      = (int*)d_ws;                            // [E]
    int*   offsets  = cnt + (E + 64);                        // [E+1]
    int*   partial  = offsets + (E + 64);                    // [<=1024]
    int*   blockoff = partial + 1024;                        // [<=1024]
    _Float16* E1p   = (_Float16*)((char*)d_ws + (4u << 20)); // [T,8] fp16  48 MB
    int*   kjp      = (int*)((char*)d_ws + (102u << 20));    // [T]     12 MB
    float* re1      = (float*)((char*)d_ws + (116u << 20));  // [E,8]  9.6 MB
    char*  wimg     = (char*)d_ws + (130u << 20);            // 320 KB fp16 images
    int*   rank     = (int*)((char*)d_ws + (134u << 20));    // [T]     12 MB

    char* wkj_i  = wimg;
    char* wji_i  = wimg + 32768;
    char* wdn_i  = wimg + 65536;    // 16 KB (128x64)
    char* wup_i  = wimg + 81920;    // 16 KB (64x128)
    char* r1w1_i = wimg + 98304;
    char* r1w2_i = wimg + 131072;
    char* wbs_i  = wimg + 163840;
    char* r2w1_i = wimg + 196608;
    char* r2w2_i = wimg + 229376;
    char* r3w1_i = wimg + 262144;
    char* r3w2_i = wimg + 294912;

    const dim3 b256(256);
    const int gB  = (E + 63) / 64;
    const int gT  = (T + 255) / 256;
    const int gT4 = (T + 1023) / 1024;
    const int NB  = (E + 1023) / 1024;
    const int gE4 = (E + 3) / 4;
    const int gR  = (E * 8 + 255) / 256;

    ProArgs P;
    P.w[0]  = {w_kj,   wkj_i,  128, 128};
    P.w[1]  = {w_ji,   wji_i,  128, 128};
    P.w[2]  = {w_down, wdn_i,  128,  64};
    P.w[3]  = {w_up,   wup_i,   64, 128};
    P.w[4]  = {r1w1,   r1w1_i, 128, 128};
    P.w[5]  = {r1w2,   r1w2_i, 128, 128};
    P.w[6]  = {w_bs,   wbs_i,  128, 128};
    P.w[7]  = {r2w1,   r2w1_i, 128, 128};
    P.w[8]  = {r2w2,   r2w2_i, 128, 128};
    P.w[9]  = {r3w1,   r3w1_i, 128, 128};
    P.w[10] = {r3w2,   r3w2_i, 128, 128};
    P.rbf = rbf; P.w_rbf1 = w_rbf1; P.re1 = re1; P.E = E;
    P.idx_ji = idx_ji; P.cnt = cnt; P.rank = rank; P.T = T;
    P.nW = 44; P.nR = gR;

    hipMemsetAsync(cnt, 0, (size_t)E * 4, stream);
    pro_kernel<<<44 + gR + gT4, b256, 0, stream>>>(P);
    scan_partial_kernel<<<NB, b256, 0, stream>>>(cnt, partial, E);
    scan_block_kernel<<<1, b256, 0, stream>>>(partial, blockoff, NB, offsets, E);
    scan_final_kernel<<<NB, b256, 0, stream>>>(cnt, blockoff, offsets, E);
    e1fill_kernel<<<gT, b256, 0, stream>>>(sbf, w_sbf1, idx_ji, idx_kj, rank, offsets, E1p, kjp, T);

    k1_kernel<<<gB, b256, 0, stream>>>(x, wkj_i, b_kj, re1, w_rbf2, wdn_i, W3, E);
    gather_kernel<<<gE4, b256, 0, stream>>>(E1p, kjp, w_sbf2, offsets, W3, W4, E);

    KBigArgs ka;
    ka.x = x; ka.W4 = W4; ka.out = OUT;
    ka.wji = wji_i; ka.wup = wup_i; ka.r1w1 = r1w1_i; ka.r1w2 = r1w2_i; ka.wbs = wbs_i;
    ka.r2w1 = r2w1_i; ka.r2w2 = r2w2_i; ka.r3w1 = r3w1_i; ka.r3w2 = r3w2_i;
    ka.bji = b_ji; ka.r1b1 = r1b1; ka.r1b2 = r1b2; ka.bbs = b_bs;
    ka.r2b1 = r2b1; ka.r2b2 = r2b2; ka.r3b1 = r3b1; ka.r3b2 = r3b2;
    ka.E = E;
    kbig_kernel<<<gB, b256, 0, stream>>>(ka);
}

// Round 23
// 987.004 us; speedup vs baseline: 1.1975x; 1.0163x over previous
//
#include <hip/hip_runtime.h>
#include <hip/hip_bf16.h>

// ---------------------------------------------------------------------------
// DimeNet++ interaction block, round 23 = round 20 verbatim (best measured:
// 989 us, absmax 0.03125). Final configuration after the 22-round ledger:
//   - pro_kernel: fused wprep | rbf1 | count_rank (block-range fusion)
//   - atomic-free CSR placement (rank = atomic return from count)
//   - e1fill: fp16 LDS staging, 7 blocks/CU
//   - gather: sequential fp16 E1 stream + fp16 W3 table, depth-1 pipeline
//   - k1/kbig: split-fp16 2-pass MFMA, fp32 t_lds, LDS-staged weights,
//     3 blocks/CU (the schedule that survived 7 structural falsifications)
// ---------------------------------------------------------------------------

typedef __attribute__((ext_vector_type(8))) _Float16 f16x8;
typedef __attribute__((ext_vector_type(4))) float f32x4;

__device__ __forceinline__ float silu_f(float v) {
    return v * __builtin_amdgcn_rcpf(1.0f + __expf(-v));
}

__device__ __forceinline__ void split44h(f32x4 a, f32x4 b, f16x8& hi, f16x8& lo) {
    float f[8] = {a[0], a[1], a[2], a[3], b[0], b[1], b[2], b[3]};
    #pragma unroll
    for (int j = 0; j < 8; ++j) {
        const _Float16 h = (_Float16)f[j];
        hi[j] = h;
        lo[j] = (_Float16)(f[j] - (float)h);
    }
}

__device__ __forceinline__ void gll16(const void* g, void* l) {
    __builtin_amdgcn_global_load_lds((const __attribute__((address_space(1))) void*)g,
                                     (__attribute__((address_space(3))) void*)l, 16, 0, 0);
}
__device__ __forceinline__ void stage8k(const char* g, _Float16* l, int lane, int wid) {
    #pragma unroll
    for (int i = 0; i < 2; ++i) {
        const int off = ((i * 4 + wid) << 10);
        gll16(g + off + lane * 16, (char*)l + off);
    }
}
__device__ __forceinline__ void stage4k(const char* g, _Float16* l, int lane, int wid) {
    const int off = (wid << 10);
    gll16(g + off + lane * 16, (char*)l + off);
}

// one 32-k step, 2-pass split-fp16 MFMA; slab: col c (64B), chunk s at
// (s ^ ((c>>1)&3)); read chunk kq  (conflict-free, r15-verified)
template<int NF>
__device__ __forceinline__ void mfma_ks(f16x8 ah, f16x8 al, const _Float16* slot,
                                        int acol, int kq, f32x4* acc) {
    #pragma unroll
    for (int n = 0; n < NF; ++n) {
        const int c = n * 16 + acol;
        const int sw = (kq ^ ((c >> 1) & 3)) << 3;
        const f16x8 bh = *(const f16x8*)&slot[c * 32 + sw];
        acc[n] = __builtin_amdgcn_mfma_f32_16x16x32_f16(ah, bh, acc[n], 0, 0, 0);
        acc[n] = __builtin_amdgcn_mfma_f32_16x16x32_f16(al, bh, acc[n], 0, 0, 0);
    }
}

__device__ __forceinline__ void tfrag(const float* tl, int rb, int q, int kq,
                                      f16x8& Ah, f16x8& Al) {
    const f32x4 ta = *(const f32x4*)&tl[rb + q * 32 + kq * 8];
    const f32x4 tb = *(const f32x4*)&tl[rb + q * 32 + kq * 8 + 4];
    split44h(ta, tb, Ah, Al);
}

__device__ __forceinline__ void tgemm4(const char* img, const char* imgnext,
                                       _Float16* sA, _Float16* sB, const float* tl, int rb,
                                       int kq, int acol, int lane, int wid, f32x4* acc)
{
    f16x8 Ah[4], Al[4];
    #pragma unroll
    for (int q = 0; q < 4; ++q) tfrag(tl, rb, q, kq, Ah[q], Al[q]);

    stage8k(img + 8192, sB, lane, wid);
    mfma_ks<8>(Ah[0], Al[0], sA, acol, kq, acc); __syncthreads();
    stage8k(img + 16384, sA, lane, wid);
    mfma_ks<8>(Ah[1], Al[1], sB, acol, kq, acc); __syncthreads();
    stage8k(img + 24576, sB, lane, wid);
    mfma_ks<8>(Ah[2], Al[2], sA, acol, kq, acc); __syncthreads();
    if (imgnext) stage8k(imgnext, sA, lane, wid);
    mfma_ks<8>(Ah[3], Al[3], sB, acol, kq, acc); __syncthreads();
}

#define TPITCH 132

// ---------------- fused prologue: wprep | rbf1 | count_rank -----------------
struct WDesc { const float* src; char* dst; int K; int N; };
struct ProArgs {
    WDesc w[11];
    const float* rbf; const float* w_rbf1; float* re1; int E;
    const int* idx_ji; int* cnt; int* rank; int T;
    int nW, nR;
};

__device__ void wprep_body(const ProArgs& P, int b) {
    const WDesc d = P.w[b >> 2];
    const int h = b & 3;
    if (h * 32 >= d.K) return;
    char* slab = d.dst + (size_t)h * d.N * 64;
    for (int idx = threadIdx.x; idx < d.N * 4; idx += 256) {
        const int c = idx >> 2, ch = idx & 3;
        f16x8 v;
        #pragma unroll
        for (int j = 0; j < 8; ++j)
            v[j] = (_Float16)d.src[(size_t)(h * 32 + ch * 8 + j) * d.N + c];
        *(f16x8*)(slab + c * 64 + ((ch ^ ((c >> 1) & 3)) << 4)) = v;
    }
}

__device__ void rbf1_body(const ProArgs& P, int b) {
    const int i = b * 256 + threadIdx.x;
    const int e = i >> 3, p = i & 7;
    if (e < P.E) {
        float s = 0.f;
        #pragma unroll
        for (int q = 0; q < 6; ++q) s = fmaf(P.rbf[e * 6 + q], P.w_rbf1[q * 8 + p], s);
        P.re1[i] = s;
    }
}

__device__ void count_rank_body(const ProArgs& P, int b) {
    const int i = (b * 256 + threadIdx.x) * 4;
    const int T = P.T;
    if (i + 3 < T) {
        const int4 j = *(const int4*)&P.idx_ji[i];
        int4 r;
        r.x = atomicAdd(&P.cnt[j.x], 1);
        r.y = atomicAdd(&P.cnt[j.y], 1);
        r.z = atomicAdd(&P.cnt[j.z], 1);
        r.w = atomicAdd(&P.cnt[j.w], 1);
        *(int4*)&P.rank[i] = r;
    } else {
        for (int k = i; k < T; ++k) P.rank[k] = atomicAdd(&P.cnt[P.idx_ji[k]], 1);
    }
}

__global__ void pro_kernel(ProArgs P) {
    const int b = blockIdx.x;
    if (b < P.nW)             wprep_body(P, b);
    else if (b < P.nW + P.nR) rbf1_body(P, b - P.nW);
    else                      count_rank_body(P, b - P.nW - P.nR);
}

// ---------------- scans ------------------------------------------------------

__global__ void scan_partial_kernel(const int* __restrict__ cnt, int* __restrict__ partial, int E) {
    __shared__ int red[256];
    const int tid = threadIdx.x;
    const int base = blockIdx.x * 1024 + tid * 4;
    int s = 0;
    #pragma unroll
    for (int i = 0; i < 4; ++i) { const int g = base + i; if (g < E) s += cnt[g]; }
    red[tid] = s;
    __syncthreads();
    for (int off = 128; off > 0; off >>= 1) {
        if (tid < off) red[tid] += red[tid + off];
        __syncthreads();
    }
    if (tid == 0) partial[blockIdx.x] = red[0];
}

__global__ void scan_block_kernel(const int* __restrict__ partial, int* __restrict__ blockoff,
                                  int NB, int* offsets, int E) {
    __shared__ int red[256];
    const int tid = threadIdx.x;
    int v[4]; int s = 0;
    #pragma unroll
    for (int i = 0; i < 4; ++i) { const int g = tid * 4 + i; v[i] = (g < NB) ? partial[g] : 0; s += v[i]; }
    red[tid] = s;
    __syncthreads();
    for (int off = 1; off < 256; off <<= 1) {
        const int add = (tid >= off) ? red[tid - off] : 0;
        __syncthreads();
        red[tid] += add;
        __syncthreads();
    }
    int excl = (tid == 0) ? 0 : red[tid - 1];
    #pragma unroll
    for (int i = 0; i < 4; ++i) { const int g = tid * 4 + i; if (g < NB) blockoff[g] = excl; excl += v[i]; }
    if (tid == 255) offsets[E] = red[255];
}

__global__ void scan_final_kernel(const int* __restrict__ cnt, const int* __restrict__ blockoff,
                                  int* __restrict__ offsets, int E) {
    __shared__ int red[256];
    const int tid = threadIdx.x;
    const int base = blockIdx.x * 1024 + tid * 4;
    int v[4]; int s = 0;
    #pragma unroll
    for (int i = 0; i < 4; ++i) { const int g = base + i; v[i] = (g < E) ? cnt[g] : 0; s += v[i]; }
    red[tid] = s;
    __syncthreads();
    for (int off = 1; off < 256; off <<= 1) {
        const int add = (tid >= off) ? red[tid - off] : 0;
        __syncthreads();
        red[tid] += add;
        __syncthreads();
    }
    int run = blockoff[blockIdx.x] + ((tid == 0) ? 0 : red[tid - 1]);
    #pragma unroll
    for (int i = 0; i < 4; ++i) {
        const int g = base + i;
        if (g < E) offsets[g] = run;
        run += v[i];
    }
}

// ---------------- e1fill (fp16 LDS staging, 7 blocks/CU) --------------------
__launch_bounds__(256, 7)
__global__ void e1fill_kernel(const float* __restrict__ sbf, const float* __restrict__ w_sbf1,
                              const int* __restrict__ idx_ji, const int* __restrict__ idx_kj,
                              const int* __restrict__ rank, const int* __restrict__ offsets,
                              _Float16* __restrict__ E1p, int* __restrict__ kjp, int T)
{
    __shared__ _Float16 s_lds[256 * 44];
    const int tid = threadIdx.x;
    const long long t0 = (long long)blockIdx.x * 256;
    const int nrow = min(256, (int)(T - t0));
    const int nel  = nrow * 42;
    const float* base = sbf + t0 * 42;

    for (int i = tid * 4; i + 3 < nel; i += 1024) {
        const float4 v = *(const float4*)&base[i];
        s_lds[(i + 0) + 2 * ((i + 0) / 42)] = (_Float16)v.x;
        s_lds[(i + 1) + 2 * ((i + 1) / 42)] = (_Float16)v.y;
        s_lds[(i + 2) + 2 * ((i + 2) / 42)] = (_Float16)v.z;
        s_lds[(i + 3) + 2 * ((i + 3) / 42)] = (_Float16)v.w;
    }
    const int tail0 = nel & ~3;
    if (tid < nel - tail0) { const int g = tail0 + tid; s_lds[g + 2 * (g / 42)] = (_Float16)base[g]; }
    __syncthreads();

    const int t = (int)t0 + tid;
    if (t >= T) return;
    const _Float16* srow = &s_lds[tid * 44];
    float e1[8] = {0.f, 0.f, 0.f, 0.f, 0.f, 0.f, 0.f, 0.f};
    #pragma unroll
    for (int q = 0; q < 42; ++q) {
        const float s = (float)srow[q];
        #pragma unroll
        for (int p = 0; p < 8; ++p) e1[p] = fmaf(s, w_sbf1[q * 8 + p], e1[p]);
    }
    f16x8 eh;
    #pragma unroll
    for (int p = 0; p < 8; ++p) eh[p] = (_Float16)e1[p];
    const int ji  = idx_ji[t];
    const int pos = offsets[ji] + rank[t];
    *(f16x8*)&E1p[(size_t)pos * 8] = eh;
    kjp[pos] = idx_kj[t];
}

// ---------------- gather: fp16 E1 stream + fp16 xkjd table ------------------
__launch_bounds__(256, 4)
__global__ void gather_kernel(const _Float16* __restrict__ E1p, const int* __restrict__ kjp,
                              const float* __restrict__ w_sbf2, const int* __restrict__ offsets,
                              const _Float16* __restrict__ xkjd, float* __restrict__ agg, int E)
{
    const int tid  = threadIdx.x;
    const int lane = tid & 63;
    const int e    = blockIdx.x * 4 + (tid >> 6);

    float w2[8];
    #pragma unroll
    for (int p = 0; p < 8; ++p) w2[p] = w_sbf2[p * 64 + lane];

    if (e >= E) return;
    const int j0 = __builtin_amdgcn_readfirstlane(offsets[e]);
    const int j1 = __builtin_amdgcn_readfirstlane(offsets[e + 1]);

    float acc = 0.f;
    if (j0 < j1) {
        int kj = __builtin_amdgcn_readfirstlane(kjp[j0]);
        f16x8 ev = *(const f16x8*)&E1p[(size_t)j0 * 8];
        float xv = (float)xkjd[(size_t)kj * 64 + lane];
        for (int j = j0; j < j1; ++j) {
            float xn = 0.f; f16x8 evn = {};
            if (j + 1 < j1) {
                const int kn = __builtin_amdgcn_readfirstlane(kjp[j + 1]);
                evn = *(const f16x8*)&E1p[(size_t)(j + 1) * 8];
                xn  = (float)xkjd[(size_t)kn * 64 + lane];
            }
            float sv = (float)ev[0] * w2[0];
            sv = fmaf((float)ev[1], w2[1], sv);
            sv = fmaf((float)ev[2], w2[2], sv);
            sv = fmaf((float)ev[3], w2[3], sv);
            sv = fmaf((float)ev[4], w2[4], sv);
            sv = fmaf((float)ev[5], w2[5], sv);
            sv = fmaf((float)ev[6], w2[6], sv);
            sv = fmaf((float)ev[7], w2[7], sv);
            acc = fmaf(xv, sv, acc);
            ev = evn; xv = xn;
        }
    }
    agg[(size_t)e * 64 + lane] = acc;
}

// ---------------- K1: W3 = silu((silu(x@w_kj+b)*rbf_e)@w_down)  (fp16 out) --
__launch_bounds__(256, 3)
__global__ void k1_kernel(const float* __restrict__ x, const char* __restrict__ wkj_i,
                          const float* __restrict__ b_kj, const float* __restrict__ re1,
                          const float* __restrict__ w_rbf2, const char* __restrict__ wdn_i,
                          _Float16* __restrict__ W3, int E)
{
    __shared__ _Float16 slotA[4096], slotB[4096];
    __shared__ float t_lds[64 * TPITCH];
    __shared__ float w2_lds[8 * 128];
    const int tid = threadIdx.x, lane = tid & 63, wid = tid >> 6;
    const int acol = lane & 15, kq = lane >> 4;
    const int rowW = blockIdx.x * 64 + wid * 16;
    const int arow = rowW + acol;
    const bool av = arow < E;

    stage8k(wkj_i, slotA, lane, wid);
    const float* xr = x + (size_t)arow * 128;
    f16x8 aH[4], aL[4];
    #pragma unroll
    for (int ks = 0; ks < 4; ++ks) {
        f32x4 a0 = f32x4{0.f, 0.f, 0.f, 0.f}, a1 = f32x4{0.f, 0.f, 0.f, 0.f};
        if (av) { a0 = *(const f32x4*)&xr[ks * 32 + kq * 8];
                  a1 = *(const f32x4*)&xr[ks * 32 + kq * 8 + 4]; }
        split44h(a0, a1, aH[ks], aL[ks]);
    }
    float bv[8];
    #pragma unroll
    for (int n = 0; n < 8; ++n) bv[n] = b_kj[n * 16 + acol];
    f32x4 e1a[4], e1b[4];
    #pragma unroll
    for (int r = 0; r < 4; ++r) {
        const int ge = rowW + kq * 4 + r;
        e1a[r] = f32x4{0.f, 0.f, 0.f, 0.f}; e1b[r] = f32x4{0.f, 0.f, 0.f, 0.f};
        if (ge < E) { e1a[r] = *(const f32x4*)&re1[(size_t)ge * 8];
                      e1b[r] = *(const f32x4*)&re1[(size_t)ge * 8 + 4]; }
    }
    for (int i = tid; i < 1024; i += 256) w2_lds[i] = w_rbf2[i];
    __syncthreads();

    f32x4 acc[8];
    #pragma unroll
    for (int n = 0; n < 8; ++n) acc[n] = f32x4{0.f, 0.f, 0.f, 0.f};

    stage8k(wkj_i + 8192, slotB, lane, wid);
    mfma_ks<8>(aH[0], aL[0], slotA, acol, kq, acc); __syncthreads();
    stage8k(wkj_i + 16384, slotA, lane, wid);
    mfma_ks<8>(aH[1], aL[1], slotB, acol, kq, acc); __syncthreads();
    stage8k(wkj_i + 24576, slotB, lane, wid);
    mfma_ks<8>(aH[2], aL[2], slotA, acol, kq, acc); __syncthreads();
    stage4k(wdn_i, slotA, lane, wid);
    mfma_ks<8>(aH[3], aL[3], slotB, acol, kq, acc); __syncthreads();

    #pragma unroll
    for (int n = 0; n < 8; ++n) {
        const int c = n * 16 + acol;
        float w2c[8];
        #pragma unroll
        for (int p = 0; p < 8; ++p) w2c[p] = w2_lds[p * 128 + c];
        #pragma unroll
        for (int r = 0; r < 4; ++r) {
            float s = e1a[r][0] * w2c[0];
            s = fmaf(e1a[r][1], w2c[1], s);
            s = fmaf(e1a[r][2], w2c[2], s);
            s = fmaf(e1a[r][3], w2c[3], s);
            s = fmaf(e1b[r][0], w2c[4], s);
            s = fmaf(e1b[r][1], w2c[5], s);
            s = fmaf(e1b[r][2], w2c[6], s);
            s = fmaf(e1b[r][3], w2c[7], s);
            t_lds[(wid * 16 + kq * 4 + r) * TPITCH + c] = silu_f(acc[n][r] + bv[n]) * s;
        }
    }
    __syncthreads();

    f32x4 acc2[4];
    #pragma unroll
    for (int n = 0; n < 4; ++n) acc2[n] = f32x4{0.f, 0.f, 0.f, 0.f};
    const int rb = (wid * 16 + acol) * TPITCH;

    f16x8 tH[4], tL[4];
    #pragma unroll
    for (int q = 0; q < 4; ++q) tfrag(t_lds, rb, q, kq, tH[q], tL[q]);

    stage4k(wdn_i + 4096, slotB, lane, wid);
    mfma_ks<4>(tH[0], tL[0], slotA, acol, kq, acc2); __syncthreads();
    stage4k(wdn_i + 8192, slotA, lane, wid);
    mfma_ks<4>(tH[1], tL[1], slotB, acol, kq, acc2); __syncthreads();
    stage4k(wdn_i + 12288, slotB, lane, wid);
    mfma_ks<4>(tH[2], tL[2], slotA, acol, kq, acc2); __syncthreads();
    mfma_ks<4>(tH[3], tL[3], slotB, acol, kq, acc2);

    #pragma unroll
    for (int n = 0; n < 4; ++n) {
        const int c = n * 16 + acol;
        #pragma unroll
        for (int r = 0; r < 4; ++r) {
            const int ge = rowW + kq * 4 + r;
            if (ge < E) W3[(size_t)ge * 64 + c] = (_Float16)silu_f(acc2[n][r]);
        }
    }
}

// ---------------- kbig: h0 -> res1 -> w_bs+skip -> res2 -> res3 (9 GEMMs) ---
struct KBigArgs {
    const float* x; const float* W4; float* out;
    const char *wji, *wup, *r1w1, *r1w2, *wbs, *r2w1, *r2w2, *r3w1, *r3w2;
    const float *bji, *r1b1, *r1b2, *bbs, *r2b1, *r2b2, *r3b1, *r3b2;
    int E;
};

__launch_bounds__(256, 3)
__global__ void kbig_kernel(KBigArgs A_)
{
    __shared__ _Float16 slotA[4096], slotB[4096];
    __shared__ float t_lds[64 * TPITCH];
    const int tid = threadIdx.x, lane = tid & 63, wid = tid >> 6;
    const int acol = lane & 15, kq = lane >> 4;
    const int rowW = blockIdx.x * 64 + wid * 16;
    const int arow = rowW + acol;
    const int E = A_.E;
    const bool av = arow < E;
    const int rb = (wid * 16 + acol) * TPITCH;

    stage8k(A_.wji, slotA, lane, wid);

    const float* xr = A_.x + (size_t)arow * 128;
    const float* wr = A_.W4 + (size_t)arow * 64;
    f16x8 aH[4], aL[4], uH[2], uL[2];
    #pragma unroll
    for (int ks = 0; ks < 4; ++ks) {
        f32x4 a0 = f32x4{0.f, 0.f, 0.f, 0.f}, a1 = f32x4{0.f, 0.f, 0.f, 0.f};
        if (av) { a0 = *(const f32x4*)&xr[ks * 32 + kq * 8];
                  a1 = *(const f32x4*)&xr[ks * 32 + kq * 8 + 4]; }
        split44h(a0, a1, aH[ks], aL[ks]);
    }
    #pragma unroll
    for (int ks = 0; ks < 2; ++ks) {
        f32x4 u0 = f32x4{0.f, 0.f, 0.f, 0.f}, u1 = f32x4{0.f, 0.f, 0.f, 0.f};
        if (av) { u0 = *(const f32x4*)&wr[ks * 32 + kq * 8];
                  u1 = *(const f32x4*)&wr[ks * 32 + kq * 8 + 4]; }
        split44h(u0, u1, uH[ks], uL[ks]);
    }
    __syncthreads();

    f32x4 acc[8];
    #pragma unroll
    for (int n = 0; n < 8; ++n) acc[n] = f32x4{0.f, 0.f, 0.f, 0.f};

    // GEMM1: x @ w_ji
    stage8k(A_.wji + 8192, slotB, lane, wid);
    mfma_ks<8>(aH[0], aL[0], slotA, acol, kq, acc); __syncthreads();
    stage8k(A_.wji + 16384, slotA, lane, wid);
    mfma_ks<8>(aH[1], aL[1], slotB, acol, kq, acc); __syncthreads();
    stage8k(A_.wji + 24576, slotB, lane, wid);
    mfma_ks<8>(aH[2], aL[2], slotA, acol, kq, acc); __syncthreads();
    stage8k(A_.wup, slotA, lane, wid);
    mfma_ks<8>(aH[3], aL[3], slotB, acol, kq, acc); __syncthreads();

    float res[8][4];
    #pragma unroll
    for (int n = 0; n < 8; ++n) {
        const float bv = A_.bji[n * 16 + acol];
        #pragma unroll
        for (int r = 0; r < 4; ++r) { res[n][r] = silu_f(acc[n][r] + bv); acc[n][r] = 0.f; }
    }

    // GEMM2: W4 @ w_up (K=64)
    stage8k(A_.wup + 8192, slotB, lane, wid);
    mfma_ks<8>(uH[0], uL[0], slotA, acol, kq, acc); __syncthreads();
    stage8k(A_.r1w1, slotA, lane, wid);
    mfma_ks<8>(uH[1], uL[1], slotB, acol, kq, acc); __syncthreads();

    #pragma unroll
    for (int n = 0; n < 8; ++n) {
        const int c = n * 16 + acol;
        #pragma unroll
        for (int r = 0; r < 4; ++r) {
            res[n][r] += silu_f(acc[n][r]);                     // h0
            t_lds[(wid * 16 + kq * 4 + r) * TPITCH + c] = res[n][r];
            acc[n][r] = 0.f;
        }
    }
    __syncthreads();

    // GEMM3: h0 @ r1w1 -> t1
    tgemm4(A_.r1w1, A_.r1w2, slotA, slotB, t_lds, rb, kq, acol, lane, wid, acc);
    #pragma unroll
    for (int n = 0; n < 8; ++n) {
        const float bv = A_.r1b1[n * 16 + acol];
        const int c = n * 16 + acol;
        #pragma unroll
        for (int r = 0; r < 4; ++r) {
            t_lds[(wid * 16 + kq * 4 + r) * TPITCH + c] = silu_f(acc[n][r] + bv);
            acc[n][r] = 0.f;
        }
    }
    __syncthreads();

    // GEMM4: t1 @ r1w2 -> t2 = h0 + silu(.)
    tgemm4(A_.r1w2, A_.wbs, slotA, slotB, t_lds, rb, kq, acol, lane, wid, acc);
    #pragma unroll
    for (int n = 0; n < 8; ++n) {
        const float bv = A_.r1b2[n * 16 + acol];
        const int c = n * 16 + acol;
        #pragma unroll
        for (int r = 0; r < 4; ++r) {
            t_lds[(wid * 16 + kq * 4 + r) * TPITCH + c] = res[n][r] + silu_f(acc[n][r] + bv);
            acc[n][r] = 0.f;
        }
    }
    __syncthreads();

    // GEMM5: t2 @ w_bs -> h2 = silu(.) + x
    tgemm4(A_.wbs, A_.r2w1, slotA, slotB, t_lds, rb, kq, acol, lane, wid, acc);
    #pragma unroll
    for (int n = 0; n < 8; ++n) {
        const float bv = A_.bbs[n * 16 + acol];
        const int c = n * 16 + acol;
        #pragma unroll
        for (int r = 0; r < 4; ++r) {
            const int ge = rowW + kq * 4 + r;
            const float xv = (ge < E) ? A_.x[(size_t)ge * 128 + c] : 0.f;
            res[n][r] = silu_f(acc[n][r] + bv) + xv;            // h2
            t_lds[(wid * 16 + kq * 4 + r) * TPITCH + c] = res[n][r];
            acc[n][r] = 0.f;
        }
    }
    __syncthreads();

    // GEMM6: h2 @ r2w1 -> t3
    tgemm4(A_.r2w1, A_.r2w2, slotA, slotB, t_lds, rb, kq, acol, lane, wid, acc);
    #pragma unroll
    for (int n = 0; n < 8; ++n) {
        const float bv = A_.r2b1[n * 16 + acol];
        const int c = n * 16 + acol;
        #pragma unroll
        for (int r = 0; r < 4; ++r) {
            t_lds[(wid * 16 + kq * 4 + r) * TPITCH + c] = silu_f(acc[n][r] + bv);
            acc[n][r] = 0.f;
        }
    }
    __syncthreads();

    // GEMM7: t3 @ r2w2 -> h3 = h2 + silu(.)
    tgemm4(A_.r2w2, A_.r3w1, slotA, slotB, t_lds, rb, kq, acol, lane, wid, acc);
    #pragma unroll
    for (int n = 0; n < 8; ++n) {
        const float bv = A_.r2b2[n * 16 + acol];
        const int c = n * 16 + acol;
        #pragma unroll
        for (int r = 0; r < 4; ++r) {
            res[n][r] += silu_f(acc[n][r] + bv);                // h3
            t_lds[(wid * 16 + kq * 4 + r) * TPITCH + c] = res[n][r];
            acc[n][r] = 0.f;
        }
    }
    __syncthreads();

    // GEMM8: h3 @ r3w1 -> t4
    tgemm4(A_.r3w1, A_.r3w2, slotA, slotB, t_lds, rb, kq, acol, lane, wid, acc);
    #pragma unroll
    for (int n = 0; n < 8; ++n) {
        const float bv = A_.r3b1[n * 16 + acol];
        const int c = n * 16 + acol;
        #pragma unroll
        for (int r = 0; r < 4; ++r) {
            t_lds[(wid * 16 + kq * 4 + r) * TPITCH + c] = silu_f(acc[n][r] + bv);
            acc[n][r] = 0.f;
        }
    }
    __syncthreads();

    // GEMM9: t4 @ r3w2 -> out = h3 + silu(.)
    tgemm4(A_.r3w2, nullptr, slotA, slotB, t_lds, rb, kq, acol, lane, wid, acc);
    #pragma unroll
    for (int n = 0; n < 8; ++n) {
        const float bv = A_.r3b2[n * 16 + acol];
        const int c = n * 16 + acol;
        #pragma unroll
        for (int r = 0; r < 4; ++r) {
            const int ge = rowW + kq * 4 + r;
            if (ge < E)
                A_.out[(size_t)ge * 128 + c] = res[n][r] + silu_f(acc[n][r] + bv);
        }
    }
}

// ---------------------------------------------------------------------------

extern "C" void kernel_launch(void* const* d_in, const int* in_sizes, int n_in,
                              void* d_out, int out_size, void* d_ws, size_t ws_size,
                              hipStream_t stream)
{
    const float* x      = (const float*)d_in[0];
    const float* rbf    = (const float*)d_in[1];
    const float* sbf    = (const float*)d_in[2];
    const int*   idx_kj = (const int*)d_in[3];
    const int*   idx_ji = (const int*)d_in[4];
    const float* w_rbf1 = (const float*)d_in[5];
    const float* w_rbf2 = (const float*)d_in[6];
    const float* w_sbf1 = (const float*)d_in[7];
    const float* w_sbf2 = (const float*)d_in[8];
    const float* w_kj   = (const float*)d_in[9];
    const float* b_kj   = (const float*)d_in[10];
    const float* w_ji   = (const float*)d_in[11];
    const float* b_ji   = (const float*)d_in[12];
    const float* w_down = (const float*)d_in[13];
    const float* w_up   = (const float*)d_in[14];
    const float* r1w1   = (const float*)d_in[15];
    const float* r1b1   = (const float*)d_in[16];
    const float* r1w2   = (const float*)d_in[17];
    const float* r1b2   = (const float*)d_in[18];
    const float* w_bs   = (const float*)d_in[19];
    const float* b_bs   = (const float*)d_in[20];
    const float* r2w1   = (const float*)d_in[21];
    const float* r2b1   = (const float*)d_in[22];
    const float* r2w2   = (const float*)d_in[23];
    const float* r2b2   = (const float*)d_in[24];
    const float* r3w1   = (const float*)d_in[25];
    const float* r3b1   = (const float*)d_in[26];
    const float* r3w2   = (const float*)d_in[27];
    const float* r3b2   = (const float*)d_in[28];

    const int E = in_sizes[0] / 128;
    const int T = in_sizes[2] / 42;

    float* OUT = (float*)d_out;
    _Float16* W3 = (_Float16*)((char*)d_ws + (size_t)E * 128 * 4);    // [E,64] fp16
    float* W4  = (float*)((char*)d_ws + (size_t)E * 128 * 4
                                      + (size_t)E * 64 * 4);          // [E,64] fp32

    int*   cnt      = (int*)d_ws;                            // [E]
    int*   offsets  = cnt + (E + 64);                        // [E+1]
    int*   partial  = offsets + (E + 64);                    // [<=1024]
    int*   blockoff = partial + 1024;                        // [<=1024]
    _Float16* E1p   = (_Float16*)((char*)d_ws + (4u << 20)); // [T,8] fp16  48 MB
    int*   kjp      = (int*)((char*)d_ws + (102u << 20));    // [T]     12 MB
    float* re1      = (float*)((char*)d_ws + (116u << 20));  // [E,8]  9.6 MB
    char*  wimg     = (char*)d_ws + (130u << 20);            // 320 KB fp16 images
    int*   rank     = (int*)((char*)d_ws + (134u << 20));    // [T]     12 MB

    char* wkj_i  = wimg;
    char* wji_i  = wimg + 32768;
    char* wdn_i  = wimg + 65536;    // 16 KB (128x64)
    char* wup_i  = wimg + 81920;    // 16 KB (64x128)
    char* r1w1_i = wimg + 98304;
    char* r1w2_i = wimg + 131072;
    char* wbs_i  = wimg + 163840;
    char* r2w1_i = wimg + 196608;
    char* r2w2_i = wimg + 229376;
    char* r3w1_i = wimg + 262144;
    char* r3w2_i = wimg + 294912;

    const dim3 b256(256);
    const int gB  = (E + 63) / 64;
    const int gT  = (T + 255) / 256;
    const int gT4 = (T + 1023) / 1024;
    const int NB  = (E + 1023) / 1024;
    const int gE4 = (E + 3) / 4;
    const int gR  = (E * 8 + 255) / 256;

    ProArgs P;
    P.w[0]  = {w_kj,   wkj_i,  128, 128};
    P.w[1]  = {w_ji,   wji_i,  128, 128};
    P.w[2]  = {w_down, wdn_i,  128,  64};
    P.w[3]  = {w_up,   wup_i,   64, 128};
    P.w[4]  = {r1w1,   r1w1_i, 128, 128};
    P.w[5]  = {r1w2,   r1w2_i, 128, 128};
    P.w[6]  = {w_bs,   wbs_i,  128, 128};
    P.w[7]  = {r2w1,   r2w1_i, 128, 128};
    P.w[8]  = {r2w2,   r2w2_i, 128, 128};
    P.w[9]  = {r3w1,   r3w1_i, 128, 128};
    P.w[10] = {r3w2,   r3w2_i, 128, 128};
    P.rbf = rbf; P.w_rbf1 = w_rbf1; P.re1 = re1; P.E = E;
    P.idx_ji = idx_ji; P.cnt = cnt; P.rank = rank; P.T = T;
    P.nW = 44; P.nR = gR;

    hipMemsetAsync(cnt, 0, (size_t)E * 4, stream);
    pro_kernel<<<44 + gR + gT4, b256, 0, stream>>>(P);
    scan_partial_kernel<<<NB, b256, 0, stream>>>(cnt, partial, E);
    scan_block_kernel<<<1, b256, 0, stream>>>(partial, blockoff, NB, offsets, E);
    scan_final_kernel<<<NB, b256, 0, stream>>>(cnt, blockoff, offsets, E);
    e1fill_kernel<<<gT, b256, 0, stream>>>(sbf, w_sbf1, idx_ji, idx_kj, rank, offsets, E1p, kjp, T);

    k1_kernel<<<gB, b256, 0, stream>>>(x, wkj_i, b_kj, re1, w_rbf2, wdn_i, W3, E);
    gather_kernel<<<gE4, b256, 0, stream>>>(E1p, kjp, w_sbf2, offsets, W3, W4, E);

    KBigArgs ka;
    ka.x = x; ka.W4 = W4; ka.out = OUT;
    ka.wji = wji_i; ka.wup = wup_i; ka.r1w1 = r1w1_i; ka.r1w2 = r1w2_i; ka.wbs = wbs_i;
    ka.r2w1 = r2w1_i; ka.r2w2 = r2w2_i; ka.r3w1 = r3w1_i; ka.r3w2 = r3w2_i;
    ka.bji = b_ji; ka.r1b1 = r1b1; ka.r1b2 = r1b2; ka.bbs = b_bs;
    ka.r2b1 = r2b1; ka.r2b2 = r2b2; ka.r3b1 = r3b1; ka.r3b2 = r3b2;
    ka.E = E;
    kbig_kernel<<<gB, b256, 0, stream>>>(ka);
}